// Round 3
// baseline (784.816 us; speedup 1.0000x reference)
//
#include <hip/hip_runtime.h>

#define NPTS 1500000
#define NVOX 262144
#define BN_EPS 1e-3f
#define NB_PT 5860          // ceil(NPTS/256)
#define NB3 11719           // ceil(NPTS/128)
#define PADROWS 1500032     // NB3*128

typedef __attribute__((ext_vector_type(8))) short bf16x8;
typedef __attribute__((ext_vector_type(4))) float f32x4;

// order-preserving float <-> uint key
__device__ __forceinline__ unsigned fkey(float f) {
    unsigned u = __float_as_uint(f);
    return u ^ ((unsigned)(((int)u) >> 31) | 0x80000000u);
}
__device__ __forceinline__ float funkey(unsigned k) {
    unsigned u = (k & 0x80000000u) ? (k ^ 0x80000000u) : ~k;
    return __uint_as_float(u);
}
#define KEY_NEG_INF 0x007FFFFFu

__device__ __forceinline__ float bf2f(unsigned short h) {
    union { unsigned u; float f; } x; x.u = ((unsigned)h) << 16; return x.f;
}
__device__ __forceinline__ unsigned short f2bf(float f) {
    union { float f; unsigned u; } x; x.f = f;
    unsigned r = x.u + 0x7FFFu + ((x.u >> 16) & 1u);
    return (unsigned short)(r >> 16);
}

__device__ __forceinline__ void make_feat(float x, float y, float z, float w,
                                          float mx, float my, float mz, float* f) {
    const float VS = 0.32f;
    const float PMX = -74.88f, PMY = -74.88f, PMZ = -2.0f;
    f[0] = x; f[1] = y; f[2] = z; f[3] = w;
    f[4] = x - mx; f[5] = y - my; f[6] = z - mz;
    float cx = floorf((x - PMX) / VS);
    float cy = floorf((y - PMY) / VS);
    float cz = floorf((z - PMZ) / VS);
    f[7] = x - (cx * VS + 0.5f * VS + PMX);
    f[8] = y - (cy * VS + 0.5f * VS + PMY);
    f[9] = z - (cz * VS + 0.5f * VS + PMZ);
    f[10] = sqrtf(x * x + y * y + z * z);
}

__global__ void k_fill(unsigned* __restrict__ p, unsigned v) {
    p[(size_t)blockIdx.x * 256 + threadIdx.x] = v;
}

__global__ void k_hist(const int* __restrict__ unq, int* __restrict__ cntv) {
    int i = blockIdx.x * blockDim.x + threadIdx.x;
    if (i < NPTS) atomicAdd(&cntv[unq[i]], 1);
}

__global__ void k_scanA(const int* __restrict__ cntv, int* __restrict__ startv,
                        int* __restrict__ bsum) {
    __shared__ int lds[256];
    int t = threadIdx.x;
    int idx4 = blockIdx.x * 256 + t;
    int4 cv = ((const int4*)cntv)[idx4];
    int s0 = cv.x, s1 = s0 + cv.y, s2 = s1 + cv.z, T = s2 + cv.w;
    lds[t] = T;
    __syncthreads();
    for (int o = 1; o < 256; o <<= 1) {
        int v = (t >= o) ? lds[t - o] : 0;
        __syncthreads();
        lds[t] += v;
        __syncthreads();
    }
    int excl = lds[t] - T;
    int4 ov; ov.x = excl; ov.y = excl + s0; ov.z = excl + s1; ov.w = excl + s2;
    ((int4*)startv)[idx4] = ov;
    if (t == 255) bsum[blockIdx.x] = lds[255];
}

__global__ void k_scanB(int* __restrict__ bsum) {
    __shared__ int lds[256];
    int t = threadIdx.x;
    int b = bsum[t];
    lds[t] = b;
    __syncthreads();
    for (int o = 1; o < 256; o <<= 1) {
        int v = (t >= o) ? lds[t - o] : 0;
        __syncthreads();
        lds[t] += v;
        __syncthreads();
    }
    bsum[t] = lds[t] - b;
}

__global__ void k_scanC(int* __restrict__ startv, int* __restrict__ offv,
                        const int* __restrict__ bsum) {
    int t = threadIdx.x;
    int idx4 = blockIdx.x * 256 + t;
    int add = bsum[blockIdx.x];
    int4 v = ((int4*)startv)[idx4];
    v.x += add; v.y += add; v.z += add; v.w += add;
    ((int4*)startv)[idx4] = v;
    ((int4*)offv)[idx4] = v;
}

__global__ void k_scatter2(const float* __restrict__ xyz, const float* __restrict__ pf,
                           const int* __restrict__ unq, int* __restrict__ offv,
                           float4* __restrict__ spts, int* __restrict__ svid) {
    int i = blockIdx.x * blockDim.x + threadIdx.x;
    if (i >= NPTS) return;
    int v = unq[i];
    int pos = atomicAdd(&offv[v], 1);
    float4 p;
    p.x = xyz[3 * i + 0]; p.y = xyz[3 * i + 1]; p.z = xyz[3 * i + 2]; p.w = pf[i];
    spts[pos] = p;
    svid[pos] = v;
}

// per-voxel xyz mean
__global__ __launch_bounds__(256) void k_vmean2(
    const float4* __restrict__ spts, const int* __restrict__ cntv,
    const int* __restrict__ startv, float4* __restrict__ vmeanv) {
    int t = threadIdx.x;
    int wave = t >> 6, lane = t & 63;
    int vb = (blockIdx.x * 4 + wave) * 16;
    for (int u = 0; u < 16; ++u) {
        int v = vb + u;
        int cnt = cntv[v];
        if (cnt == 0) continue;
        int st = startv[v];
        float sx = 0, sy = 0, sz = 0;
        for (int j = lane; j < cnt; j += 64) {
            float4 p = spts[st + j];
            sx += p.x; sy += p.y; sz += p.z;
        }
        #pragma unroll
        for (int o = 32; o; o >>= 1) {
            sx += __shfl_xor(sx, o); sy += __shfl_xor(sy, o); sz += __shfl_xor(sz, o);
        }
        if (lane == 0) {
            float inv = 1.0f / (float)cnt;
            vmeanv[v] = make_float4(sx * inv, sy * inv, sz * inv, 0.f);
        }
    }
}

// point-parallel layer 1: feat -> y1 (raw, bf16)
__global__ __launch_bounds__(256) void k_y1(
    const float4* __restrict__ spts, const int* __restrict__ svid,
    const float4* __restrict__ vmeanv, const float* __restrict__ w1,
    unsigned* __restrict__ y1u) {
    int i = blockIdx.x * 256 + threadIdx.x;
    if (i >= NPTS) return;
    float4 p = spts[i];
    int v = svid[i];
    float4 vm = vmeanv[v];
    float f[11];
    make_feat(p.x, p.y, p.z, p.w, vm.x, vm.y, vm.z, f);
    float yv[32];
    #pragma unroll
    for (int c = 0; c < 32; ++c) yv[c] = 0.f;
    #pragma unroll
    for (int k = 0; k < 11; ++k) {
        float fk = f[k];
        #pragma unroll
        for (int c = 0; c < 32; ++c) yv[c] = fmaf(fk, w1[k * 32 + c], yv[c]);
    }
    unsigned o[16];
    #pragma unroll
    for (int q = 0; q < 16; ++q)
        o[q] = (unsigned)f2bf(yv[2 * q]) | ((unsigned)f2bf(yv[2 * q + 1]) << 16);
    uint4* dst = (uint4*)(y1u + (size_t)i * 16);
    dst[0] = make_uint4(o[0], o[1], o[2], o[3]);
    dst[1] = make_uint4(o[4], o[5], o[6], o[7]);
    dst[2] = make_uint4(o[8], o[9], o[10], o[11]);
    dst[3] = make_uint4(o[12], o[13], o[14], o[15]);
}

// per-voxel raw y1 max + BN1 stats
__global__ __launch_bounds__(256) void k_stats1max(
    const unsigned* __restrict__ y1u, const int* __restrict__ cntv,
    const int* __restrict__ startv, unsigned short* __restrict__ xmraw,
    float* __restrict__ stats) {
    __shared__ float accs[64];
    int t = threadIdx.x;
    if (t < 64) accs[t] = 0.f;
    __syncthreads();
    int wave = t >> 6, lane = t & 63;
    int c = lane & 31, s = lane >> 5;
    int vb = (blockIdx.x * 4 + wave) * 16;
    float sa = 0.f, sq = 0.f;
    for (int u = 0; u < 16; ++u) {
        int v = vb + u;
        int cnt = cntv[v];
        int st = startv[v];
        float m = -INFINITY;
        for (int j = s; j < cnt; j += 2) {
            unsigned uu = y1u[(size_t)(st + j) * 16 + (c >> 1)];
            float y = bf2f((unsigned short)((c & 1) ? (uu >> 16) : (uu & 0xFFFF)));
            m = fmaxf(m, y); sa += y; sq += y * y;
        }
        m = fmaxf(m, __shfl_xor(m, 32));
        if (lane < 32) xmraw[(size_t)v * 32 + c] = f2bf(m);
    }
    atomicAdd(&accs[c], sa);
    atomicAdd(&accs[32 + c], sq);
    __syncthreads();
    if (t < 64) atomicAdd(&stats[t], accs[t]);
}

__global__ void k_fin1(float* __restrict__ stats, const float* __restrict__ g1,
                       const float* __restrict__ b1) {
    int c = threadIdx.x;
    if (c >= 32) return;
    float invn = 1.0f / (float)NPTS;
    float mu = stats[c] * invn;
    float var = stats[32 + c] * invn - mu * mu;
    float sc = rsqrtf(var + BN_EPS) * g1[c];
    stats[64 + c] = sc;
    stats[96 + c] = b1[c] - mu * sc;
}

__device__ __forceinline__ void flushseg(int v, float m, bool atom, int c,
                                         unsigned* __restrict__ okeys) {
    if ((unsigned)v >= (unsigned)NVOX) return;
    if (atom) atomicMax(&okeys[(size_t)v * 64 + c], fkey(m));
    else okeys[(size_t)v * 64 + c] = fkey(m);
}

// layer 2 via MFMA over 128 sorted rows/block + segmented max + BN2 stats
__global__ __launch_bounds__(256) void k_l2(
    const unsigned* __restrict__ y1u, const int* __restrict__ svid,
    const unsigned short* __restrict__ xmraw, const float* __restrict__ w2,
    float* __restrict__ stats, unsigned* __restrict__ okeys) {
    __shared__ unsigned Abuf[128 * 32];   // [row][64 bf16] chunks XOR-swizzled
    __shared__ unsigned Bbuf[64 * 32];    // Bt [col][64 k bf16] swizzled
    __shared__ float y2t[64 * 128];       // [col][row] f32, chunk-swizzled
    __shared__ int vids[128];
    __shared__ float sc1s[32], sh1s[32];
    __shared__ int hv[4][64]; __shared__ float hk[4][64];
    __shared__ int tv[4][64]; __shared__ float tk[4][64];
    __shared__ unsigned short sgl[4][64];
    __shared__ float accs[128];

    int t = threadIdx.x;
    if (t < 32) { sc1s[t] = stats[64 + t]; sh1s[t] = stats[96 + t]; }
    if (t < 128) accs[t] = 0.f;
    __syncthreads();
    long brow = (long)blockIdx.x * 128;

    // ---- build Bt (w2 transposed, bf16, swizzled) ----
    {
        int c = t & 63, kc = (t >> 6) * 16;
        unsigned ob[8];
        #pragma unroll
        for (int q = 0; q < 8; ++q) {
            float wa = w2[(kc + 2 * q) * 64 + c];
            float wb = w2[(kc + 2 * q + 1) * 64 + c];
            ob[q] = (unsigned)f2bf(wa) | ((unsigned)f2bf(wb) << 16);
        }
        int ch0 = (t >> 6) * 2;
        ((uint4*)Bbuf)[c * 8 + (ch0 ^ (c & 7))] = make_uint4(ob[0], ob[1], ob[2], ob[3]);
        ((uint4*)Bbuf)[c * 8 + ((ch0 + 1) ^ (c & 7))] = make_uint4(ob[4], ob[5], ob[6], ob[7]);
    }

    // ---- build A = [z1 | xm] bf16 ----
    {
        int row2 = t >> 1;
        int half = t & 1;
        long grow = brow + row2;
        int vid = (grow < NPTS) ? svid[grow] : -1;
        unsigned outv[16];
        if (half == 0) {
            if (grow < NPTS) {
                const uint4* src = (const uint4*)(y1u + (size_t)grow * 16);
                #pragma unroll
                for (int q = 0; q < 4; ++q) {
                    uint4 uu = src[q];
                    unsigned in4[4] = {uu.x, uu.y, uu.z, uu.w};
                    #pragma unroll
                    for (int e = 0; e < 4; ++e) {
                        int c0 = q * 8 + 2 * e;
                        float z0 = fmaxf(0.f, fmaf(bf2f((unsigned short)(in4[e] & 0xFFFF)), sc1s[c0], sh1s[c0]));
                        float z1 = fmaxf(0.f, fmaf(bf2f((unsigned short)(in4[e] >> 16)), sc1s[c0 + 1], sh1s[c0 + 1]));
                        outv[q * 4 + e] = (unsigned)f2bf(z0) | ((unsigned)f2bf(z1) << 16);
                    }
                }
            } else {
                #pragma unroll
                for (int q = 0; q < 16; ++q) outv[q] = 0u;
            }
            uint4* arow = (uint4*)(Abuf + row2 * 32);
            #pragma unroll
            for (int ch = 0; ch < 4; ++ch)
                arow[ch ^ (row2 & 7)] = make_uint4(outv[ch * 4], outv[ch * 4 + 1],
                                                   outv[ch * 4 + 2], outv[ch * 4 + 3]);
        } else {
            vids[row2] = vid;
            if (vid >= 0) {
                const uint4* src = (const uint4*)(xmraw + (size_t)vid * 32);
                #pragma unroll
                for (int q = 0; q < 4; ++q) {
                    uint4 uu = src[q];
                    unsigned in4[4] = {uu.x, uu.y, uu.z, uu.w};
                    #pragma unroll
                    for (int e = 0; e < 4; ++e) {
                        int c0 = q * 8 + 2 * e;
                        float z0 = fmaxf(0.f, fmaf(bf2f((unsigned short)(in4[e] & 0xFFFF)), sc1s[c0], sh1s[c0]));
                        float z1 = fmaxf(0.f, fmaf(bf2f((unsigned short)(in4[e] >> 16)), sc1s[c0 + 1], sh1s[c0 + 1]));
                        outv[q * 4 + e] = (unsigned)f2bf(z0) | ((unsigned)f2bf(z1) << 16);
                    }
                }
            } else {
                #pragma unroll
                for (int q = 0; q < 16; ++q) outv[q] = 0u;
            }
            uint4* arow = (uint4*)(Abuf + row2 * 32);
            #pragma unroll
            for (int ch = 0; ch < 4; ++ch)
                arow[(ch + 4) ^ (row2 & 7)] = make_uint4(outv[ch * 4], outv[ch * 4 + 1],
                                                         outv[ch * 4 + 2], outv[ch * 4 + 3]);
        }
    }
    __syncthreads();

    // ---- MFMA: D[128 rows][64 cols] = A @ B ----
    {
        int wave = t >> 6, lane = t & 63;
        int wbase = wave * 32;
        int lr = lane & 15, lk = lane >> 4;
        bf16x8 afr[2][2], bfr[4][2];
        #pragma unroll
        for (int mt = 0; mt < 2; ++mt)
            #pragma unroll
            for (int kt = 0; kt < 2; ++kt) {
                int row = wbase + mt * 16 + lr;
                int ch = kt * 4 + lk;
                uint4 uu = ((const uint4*)(Abuf + row * 32))[ch ^ (row & 7)];
                afr[mt][kt] = __builtin_bit_cast(bf16x8, uu);
            }
        #pragma unroll
        for (int nt = 0; nt < 4; ++nt)
            #pragma unroll
            for (int kt = 0; kt < 2; ++kt) {
                int col = nt * 16 + lr;
                int ch = kt * 4 + lk;
                uint4 uu = ((const uint4*)(Bbuf + col * 32))[ch ^ (col & 7)];
                bfr[nt][kt] = __builtin_bit_cast(bf16x8, uu);
            }
        f32x4 acc[2][4];
        #pragma unroll
        for (int mt = 0; mt < 2; ++mt)
            #pragma unroll
            for (int nt = 0; nt < 4; ++nt) {
                acc[mt][nt] = (f32x4){0.f, 0.f, 0.f, 0.f};
                #pragma unroll
                for (int kt = 0; kt < 2; ++kt)
                    acc[mt][nt] = __builtin_amdgcn_mfma_f32_16x16x32_bf16(
                        afr[mt][kt], bfr[nt][kt], acc[mt][nt], 0, 0, 0);
            }
        // write y2t[col][row], 4 rows per f32x4 chunk, swizzled
        #pragma unroll
        for (int mt = 0; mt < 2; ++mt)
            #pragma unroll
            for (int nt = 0; nt < 4; ++nt) {
                int col = nt * 16 + lr;
                int rowb = wbase + mt * 16 + lk * 4;
                int ch = rowb >> 2;
                ((f32x4*)(y2t + col * 128))[ch ^ (col & 31)] = acc[mt][nt];
            }
    }
    __syncthreads();

    // ---- segmented scan over 32 rows per thread ----
    {
        int c = t & 63, ck = t >> 6;
        int r0 = ck * 32;
        float sa = 0.f, sq = 0.f;
        int cur_v = -2; float cur_m = 0.f;
        int hvv = -2; float hkk = 0.f;
        bool first_done = false;
        #pragma unroll
        for (int q = 0; q < 8; ++q) {
            int ch = ck * 8 + q;
            f32x4 dv = ((const f32x4*)(y2t + c * 128))[ch ^ (c & 31)];
            #pragma unroll
            for (int e = 0; e < 4; ++e) {
                int r = r0 + q * 4 + e;
                int v = vids[r];
                float d = dv[e];
                if (v >= 0) { sa += d; sq += d * d; }
                if (q == 0 && e == 0) { cur_v = v; cur_m = d; }
                else if (v == cur_v) cur_m = fmaxf(cur_m, d);
                else {
                    if (!first_done) { hvv = cur_v; hkk = cur_m; first_done = true; }
                    else if ((unsigned)cur_v < (unsigned)NVOX)
                        okeys[(size_t)cur_v * 64 + c] = fkey(cur_m);
                    cur_v = v; cur_m = d;
                }
            }
        }
        hv[ck][c] = first_done ? hvv : cur_v;
        hk[ck][c] = first_done ? hkk : cur_m;
        tv[ck][c] = cur_v; tk[ck][c] = cur_m;
        sgl[ck][c] = first_done ? 0 : 1;
        atomicAdd(&accs[c], sa);
        atomicAdd(&accs[64 + c], sq);
    }
    __syncthreads();

    // ---- merge chunk heads/tails + stats flush ----
    if (t < 64) {
        int cv = hv[0][t]; float cm = hk[0][t];
        bool from_start = true;
        #pragma unroll
        for (int k2 = 0; k2 < 4; ++k2) {
            if (k2 > 0) {
                int nv = hv[k2][t]; float nm = hk[k2][t];
                if (nv == cv) cm = fmaxf(cm, nm);
                else {
                    flushseg(cv, cm, from_start, t, okeys);
                    cv = nv; cm = nm; from_start = false;
                }
            }
            if (!sgl[k2][t]) {
                flushseg(cv, cm, from_start, t, okeys);
                cv = tv[k2][t]; cm = tk[k2][t]; from_start = false;
            }
        }
        flushseg(cv, cm, true, t, okeys);
    }
    if (t < 128) atomicAdd(&stats[128 + t], accs[t]);
}

__global__ void k_fin2(float* __restrict__ stats, const float* __restrict__ g2,
                       const float* __restrict__ b2) {
    int c = threadIdx.x;
    if (c >= 64) return;
    float invn = 1.0f / (float)NPTS;
    float mu = stats[128 + c] * invn;
    float var = stats[192 + c] * invn - mu * mu;
    float sc = rsqrtf(var + BN_EPS) * g2[c];
    stats[256 + c] = sc;
    stats[320 + c] = b2[c] - mu * sc;
}

__global__ void k_out(unsigned* __restrict__ okeys, const float* __restrict__ stats) {
    int idx = blockIdx.x * 256 + threadIdx.x;
    int c = idx & 63;
    float raw = funkey(okeys[idx]);
    float val = fmaxf(0.0f, fmaf(raw, stats[256 + c], stats[320 + c]));
    ((float*)okeys)[idx] = val;
}

extern "C" void kernel_launch(void* const* d_in, const int* in_sizes, int n_in,
                              void* d_out, int out_size, void* d_ws, size_t ws_size,
                              hipStream_t stream) {
    const float* xyz = (const float*)d_in[0];
    const float* pf  = (const float*)d_in[1];
    const float* w1  = (const float*)d_in[2];
    const float* g1  = (const float*)d_in[3];
    const float* b1  = (const float*)d_in[4];
    const float* w2  = (const float*)d_in[5];
    const float* g2  = (const float*)d_in[6];
    const float* b2  = (const float*)d_in[7];
    const int*   unq = (const int*)d_in[8];

    float4* spts   = (float4*)d_ws;                        // NPTS float4 (24 MB)
    unsigned short* xmraw = (unsigned short*)d_ws;         // NVOX*32 bf16 (16 MB, aliases spts after k_y1)
    float4* vmeanv = spts + NPTS;                          // NVOX float4 (4 MB)
    unsigned* y1u  = (unsigned*)(vmeanv + NVOX);           // NPTS*16 uints (96 MB)
    int* svid      = (int*)(y1u + (size_t)NPTS * 16);      // PADROWS ints (6 MB)
    int* cntv      = svid + PADROWS;                       // NVOX
    int* startv    = cntv + NVOX;                          // NVOX
    int* offv      = startv + NVOX;                        // NVOX
    int* bsum      = offv + NVOX;                          // 256
    float* stats   = (float*)(bsum + 256);                 // 1024

    unsigned* okeys = (unsigned*)d_out;

    hipMemsetAsync(cntv, 0, (size_t)NVOX * sizeof(int), stream);
    hipMemsetAsync(stats, 0, 1024 * sizeof(float), stream);
    hipMemsetAsync(svid + NPTS, 0xFF, (PADROWS - NPTS) * sizeof(int), stream);
    k_fill<<<NVOX * 64 / 256, 256, 0, stream>>>(okeys, KEY_NEG_INF);

    k_hist<<<NB_PT, 256, 0, stream>>>(unq, cntv);
    k_scanA<<<256, 256, 0, stream>>>(cntv, startv, bsum);
    k_scanB<<<1, 256, 0, stream>>>(bsum);
    k_scanC<<<256, 256, 0, stream>>>(startv, offv, bsum);
    k_scatter2<<<NB_PT, 256, 0, stream>>>(xyz, pf, unq, offv, spts, svid);
    k_vmean2<<<4096, 256, 0, stream>>>(spts, cntv, startv, vmeanv);
    k_y1<<<NB_PT, 256, 0, stream>>>(spts, svid, vmeanv, w1, y1u);
    k_stats1max<<<4096, 256, 0, stream>>>(y1u, cntv, startv, xmraw, stats);
    k_fin1<<<1, 64, 0, stream>>>(stats, g1, b1);
    k_l2<<<NB3, 256, 0, stream>>>(y1u, svid, xmraw, w2, stats, okeys);
    k_fin2<<<1, 64, 0, stream>>>(stats, g2, b2);
    k_out<<<NVOX * 64 / 256, 256, 0, stream>>>(okeys, stats);
}

// Round 4
// 769.871 us; speedup vs baseline: 1.0194x; 1.0194x over previous
//
#include <hip/hip_runtime.h>

#define NPTS 1500000
#define NVOX 262144
#define BN_EPS 1e-3f
#define PAD 1500160        // NB_PT*256 == NB_L2*128
#define NB_PT 5860
#define NB_L2 11720

typedef __attribute__((ext_vector_type(8))) short bf16x8;
typedef __attribute__((ext_vector_type(4))) float f32x4;

__device__ __forceinline__ unsigned fkey(float f) {
    unsigned u = __float_as_uint(f);
    return u ^ ((unsigned)(((int)u) >> 31) | 0x80000000u);
}
__device__ __forceinline__ float funkey(unsigned k) {
    unsigned u = (k & 0x80000000u) ? (k ^ 0x80000000u) : ~k;
    return __uint_as_float(u);
}
#define KEY_NEG_INF 0x007FFFFFu

__device__ __forceinline__ float bf2f(unsigned short h) {
    union { unsigned u; float f; } x; x.u = ((unsigned)h) << 16; return x.f;
}
__device__ __forceinline__ unsigned short f2bf(float f) {
    union { float f; unsigned u; } x; x.f = f;
    unsigned r = x.u + 0x7FFFu + ((x.u >> 16) & 1u);
    return (unsigned short)(r >> 16);
}

__device__ __forceinline__ void make_feat(float x, float y, float z, float w,
                                          float mx, float my, float mz, float* f) {
    const float VS = 0.32f;
    const float PMX = -74.88f, PMY = -74.88f, PMZ = -2.0f;
    f[0] = x; f[1] = y; f[2] = z; f[3] = w;
    f[4] = x - mx; f[5] = y - my; f[6] = z - mz;
    float cx = floorf((x - PMX) / VS);
    float cy = floorf((y - PMY) / VS);
    float cz = floorf((z - PMZ) / VS);
    f[7] = x - (cx * VS + 0.5f * VS + PMX);
    f[8] = y - (cy * VS + 0.5f * VS + PMY);
    f[9] = z - (cz * VS + 0.5f * VS + PMZ);
    f[10] = sqrtf(x * x + y * y + z * z);
}

__global__ void k_fill(unsigned* __restrict__ p, unsigned v) {
    p[(size_t)blockIdx.x * 256 + threadIdx.x] = v;
}

__global__ void k_hist(const int* __restrict__ unq, int* __restrict__ cntv) {
    int i = blockIdx.x * blockDim.x + threadIdx.x;
    if (i < NPTS) atomicAdd(&cntv[unq[i]], 1);
}

__global__ void k_scanA(const int* __restrict__ cntv, int* __restrict__ startv,
                        int* __restrict__ bsum) {
    __shared__ int lds[256];
    int t = threadIdx.x;
    int idx4 = blockIdx.x * 256 + t;
    int4 cv = ((const int4*)cntv)[idx4];
    int s0 = cv.x, s1 = s0 + cv.y, s2 = s1 + cv.z, T = s2 + cv.w;
    lds[t] = T;
    __syncthreads();
    for (int o = 1; o < 256; o <<= 1) {
        int v = (t >= o) ? lds[t - o] : 0;
        __syncthreads();
        lds[t] += v;
        __syncthreads();
    }
    int excl = lds[t] - T;
    int4 ov; ov.x = excl; ov.y = excl + s0; ov.z = excl + s1; ov.w = excl + s2;
    ((int4*)startv)[idx4] = ov;
    if (t == 255) bsum[blockIdx.x] = lds[255];
}

__global__ void k_scanB(int* __restrict__ bsum) {
    __shared__ int lds[256];
    int t = threadIdx.x;
    int b = bsum[t];
    lds[t] = b;
    __syncthreads();
    for (int o = 1; o < 256; o <<= 1) {
        int v = (t >= o) ? lds[t - o] : 0;
        __syncthreads();
        lds[t] += v;
        __syncthreads();
    }
    bsum[t] = lds[t] - b;
}

__global__ void k_scanC(int* __restrict__ startv, int* __restrict__ offv,
                        const int* __restrict__ bsum) {
    int t = threadIdx.x;
    int idx4 = blockIdx.x * 256 + t;
    int add = bsum[blockIdx.x];
    int4 v = ((int4*)startv)[idx4];
    v.x += add; v.y += add; v.z += add; v.w += add;
    ((int4*)startv)[idx4] = v;
    ((int4*)offv)[idx4] = v;
}

__global__ void k_scatter2(const float* __restrict__ xyz, const float* __restrict__ pf,
                           const int* __restrict__ unq, int* __restrict__ offv,
                           float4* __restrict__ spts, int* __restrict__ svid) {
    int i = blockIdx.x * blockDim.x + threadIdx.x;
    if (i >= NPTS) return;
    int v = unq[i];
    int pos = atomicAdd(&offv[v], 1);
    float4 p;
    p.x = xyz[3 * i + 0]; p.y = xyz[3 * i + 1]; p.z = xyz[3 * i + 2]; p.w = pf[i];
    spts[pos] = p;
    svid[pos] = v;
}

__global__ __launch_bounds__(256) void k_vmean2(
    const float4* __restrict__ spts, const int* __restrict__ cntv,
    const int* __restrict__ startv, float4* __restrict__ vmeanv) {
    int t = threadIdx.x;
    int wave = t >> 6, lane = t & 63;
    int vb = (blockIdx.x * 4 + wave) * 16;
    for (int u = 0; u < 16; ++u) {
        int v = vb + u;
        int cnt = cntv[v];
        if (cnt == 0) continue;
        int st = startv[v];
        float sx = 0, sy = 0, sz = 0;
        for (int j = lane; j < cnt; j += 64) {
            float4 p = spts[st + j];
            sx += p.x; sy += p.y; sz += p.z;
        }
        #pragma unroll
        for (int o = 32; o; o >>= 1) {
            sx += __shfl_xor(sx, o); sy += __shfl_xor(sy, o); sz += __shfl_xor(sz, o);
        }
        if (lane == 0) {
            float inv = 1.0f / (float)cnt;
            vmeanv[v] = make_float4(sx * inv, sy * inv, sz * inv, 0.f);
        }
    }
}

__device__ __forceinline__ void flush32(int v, float m, bool atom, int c,
                                        unsigned* __restrict__ xm) {
    if ((unsigned)v >= (unsigned)NVOX) return;
    if (atom) atomicMax(&xm[(size_t)v * 32 + c], fkey(m));
    else xm[(size_t)v * 32 + c] = fkey(m);
}
__device__ __forceinline__ void flush64(int v, float m, bool atom, int c,
                                        unsigned* __restrict__ ok) {
    if ((unsigned)v >= (unsigned)NVOX) return;
    if (atom) atomicMax(&ok[(size_t)v * 64 + c], fkey(m));
    else ok[(size_t)v * 64 + c] = fkey(m);
}

// passA: per-point layer-1 (f32) -> BN1 stats + per-voxel raw-y1 max (f32 fkey)
__global__ __launch_bounds__(256) void k_passA(
    const float4* __restrict__ spts, const int* __restrict__ svid,
    const float4* __restrict__ vmeanv, const float* __restrict__ w1,
    unsigned* __restrict__ xmraw, float* __restrict__ stats) {
    __shared__ float ylds[256 * 32];
    __shared__ int vlds[256];
    __shared__ float accs[64];
    __shared__ int hv[8][32]; __shared__ float hk[8][32];
    __shared__ int tv[8][32]; __shared__ float tk[8][32];
    __shared__ unsigned char sgl[8][32];
    int t = threadIdx.x;
    if (t < 64) accs[t] = 0.f;
    long grow = (long)blockIdx.x * 256 + t;
    int vid = (grow < NPTS) ? svid[grow] : -1;
    vlds[t] = vid;
    float yv[32];
    #pragma unroll
    for (int c = 0; c < 32; ++c) yv[c] = 0.f;
    if (vid >= 0) {
        float4 p = spts[grow];
        float4 vm = vmeanv[vid];
        float f[11];
        make_feat(p.x, p.y, p.z, p.w, vm.x, vm.y, vm.z, f);
        #pragma unroll
        for (int k = 0; k < 11; ++k) {
            float fk = f[k];
            #pragma unroll
            for (int c = 0; c < 32; ++c) yv[c] = fmaf(fk, w1[k * 32 + c], yv[c]);
        }
    }
    f32x4* yr = (f32x4*)&ylds[t * 32];
    #pragma unroll
    for (int q = 0; q < 8; ++q) {
        f32x4 vv = {yv[4 * q], yv[4 * q + 1], yv[4 * q + 2], yv[4 * q + 3]};
        yr[q ^ (t & 7)] = vv;
    }
    __syncthreads();
    {
        int c = t & 31, ck = t >> 5;
        int cq = c >> 2, ce = c & 3;
        float sa = 0.f, sq = 0.f;
        int cur_v = -2; float cur_m = 0.f;
        int hvv = -2; float hkk = 0.f; bool fd = false;
        for (int s = 0; s < 32; ++s) {
            int r = ck * 32 + s;
            float y = ylds[r * 32 + 4 * (cq ^ (r & 7)) + ce];
            int v = vlds[r];
            sa += y; sq += y * y;
            if (s == 0) { cur_v = v; cur_m = y; }
            else if (v == cur_v) cur_m = fmaxf(cur_m, y);
            else {
                if (!fd) { hvv = cur_v; hkk = cur_m; fd = true; }
                else if ((unsigned)cur_v < (unsigned)NVOX)
                    xmraw[(size_t)cur_v * 32 + c] = fkey(cur_m);
                cur_v = v; cur_m = y;
            }
        }
        hv[ck][c] = fd ? hvv : cur_v; hk[ck][c] = fd ? hkk : cur_m;
        tv[ck][c] = cur_v; tk[ck][c] = cur_m; sgl[ck][c] = fd ? 0 : 1;
        atomicAdd(&accs[c], sa);
        atomicAdd(&accs[32 + c], sq);
    }
    __syncthreads();
    if (t < 32) {
        int cv = hv[0][t]; float cm = hk[0][t]; bool fs = true;
        #pragma unroll
        for (int k2 = 0; k2 < 8; ++k2) {
            if (k2 > 0) {
                int nv = hv[k2][t]; float nm = hk[k2][t];
                if (nv == cv) cm = fmaxf(cm, nm);
                else { flush32(cv, cm, fs, t, xmraw); cv = nv; cm = nm; fs = false; }
            }
            if (!sgl[k2][t]) {
                flush32(cv, cm, fs, t, xmraw);
                cv = tv[k2][t]; cm = tk[k2][t]; fs = false;
            }
        }
        flush32(cv, cm, true, t, xmraw);
    }
    if (t < 64) atomicAdd(&stats[t], accs[t]);
}

__global__ void k_fin1(float* __restrict__ stats, const float* __restrict__ g1,
                       const float* __restrict__ b1) {
    int c = threadIdx.x;
    if (c >= 32) return;
    float invn = 1.0f / (float)NPTS;
    float mu = stats[c] * invn;
    float var = stats[32 + c] * invn - mu * mu;
    float sc = rsqrtf(var + BN_EPS) * g1[c];
    stats[64 + c] = sc;
    stats[96 + c] = b1[c] - mu * sc;
}

// k_l2: in-block z1 + gathered xm -> MFMA y2 -> segmented max + BN2 stats
__global__ __launch_bounds__(256) void k_l2(
    const float4* __restrict__ spts, const int* __restrict__ svid,
    const float4* __restrict__ vmeanv, const float* __restrict__ w1,
    const unsigned* __restrict__ xmraw, const float* __restrict__ w2,
    float* __restrict__ stats, unsigned* __restrict__ okeys) {
    __shared__ unsigned Abuf[128 * 32];
    __shared__ unsigned Bbuf[64 * 32];
    __shared__ unsigned y2t[64 * 64];       // bf16 pairs [col][row/2] swizzled
    __shared__ int vids[128];
    __shared__ float sc1s[32], sh1s[32];
    __shared__ float accs[128];
    __shared__ int hv[4][64]; __shared__ float hk[4][64];
    __shared__ int tv[4][64]; __shared__ float tk[4][64];
    __shared__ unsigned char sgl[4][64];
    int t = threadIdx.x;
    if (t < 32) { sc1s[t] = stats[64 + t]; sh1s[t] = stats[96 + t]; }
    if (t < 128) accs[t] = 0.f;
    __syncthreads();
    long brow = (long)blockIdx.x * 128;

    // B = w2^T bf16, swizzled
    {
        int c = t & 63, kc = (t >> 6) * 16;
        unsigned ob[8];
        #pragma unroll
        for (int q = 0; q < 8; ++q) {
            float wa = w2[(kc + 2 * q) * 64 + c];
            float wb = w2[(kc + 2 * q + 1) * 64 + c];
            ob[q] = (unsigned)f2bf(wa) | ((unsigned)f2bf(wb) << 16);
        }
        int ch0 = (t >> 6) * 2;
        ((uint4*)Bbuf)[c * 8 + (ch0 ^ (c & 7))] = make_uint4(ob[0], ob[1], ob[2], ob[3]);
        ((uint4*)Bbuf)[c * 8 + ((ch0 + 1) ^ (c & 7))] = make_uint4(ob[4], ob[5], ob[6], ob[7]);
    }

    // A = [z1 | z(xm)] bf16: waves 0-1 compute z1 (layer-1), waves 2-3 gather xm
    if (t < 128) {
        int row = t;
        long grow = brow + row;
        int vid = (grow < NPTS) ? svid[grow] : -1;
        unsigned outv[16];
        if (vid >= 0) {
            float4 p = spts[grow];
            float4 vm = vmeanv[vid];
            float f[11];
            make_feat(p.x, p.y, p.z, p.w, vm.x, vm.y, vm.z, f);
            float yv[32];
            #pragma unroll
            for (int c = 0; c < 32; ++c) yv[c] = 0.f;
            #pragma unroll
            for (int k = 0; k < 11; ++k) {
                float fk = f[k];
                #pragma unroll
                for (int c = 0; c < 32; ++c) yv[c] = fmaf(fk, w1[k * 32 + c], yv[c]);
            }
            #pragma unroll
            for (int q = 0; q < 16; ++q) {
                float z0 = fmaxf(0.f, fmaf(yv[2 * q], sc1s[2 * q], sh1s[2 * q]));
                float z1 = fmaxf(0.f, fmaf(yv[2 * q + 1], sc1s[2 * q + 1], sh1s[2 * q + 1]));
                outv[q] = (unsigned)f2bf(z0) | ((unsigned)f2bf(z1) << 16);
            }
        } else {
            #pragma unroll
            for (int q = 0; q < 16; ++q) outv[q] = 0u;
        }
        uint4* arow = (uint4*)(Abuf + row * 32);
        #pragma unroll
        for (int ch = 0; ch < 4; ++ch)
            arow[ch ^ (row & 7)] = make_uint4(outv[ch * 4], outv[ch * 4 + 1],
                                              outv[ch * 4 + 2], outv[ch * 4 + 3]);
    } else {
        int row = t - 128;
        long grow = brow + row;
        int vid = (grow < NPTS) ? svid[grow] : -1;
        vids[row] = vid;
        unsigned outv[16];
        if (vid >= 0) {
            const uint4* src = (const uint4*)(xmraw + (size_t)vid * 32);
            #pragma unroll
            for (int q = 0; q < 8; ++q) {
                uint4 uu = src[q];
                unsigned w4[4] = {uu.x, uu.y, uu.z, uu.w};
                #pragma unroll
                for (int e = 0; e < 2; ++e) {
                    int c0 = q * 4 + 2 * e;
                    float z0 = fmaxf(0.f, fmaf(funkey(w4[2 * e]), sc1s[c0], sh1s[c0]));
                    float z1 = fmaxf(0.f, fmaf(funkey(w4[2 * e + 1]), sc1s[c0 + 1], sh1s[c0 + 1]));
                    outv[q * 2 + e] = (unsigned)f2bf(z0) | ((unsigned)f2bf(z1) << 16);
                }
            }
        } else {
            #pragma unroll
            for (int q = 0; q < 16; ++q) outv[q] = 0u;
        }
        uint4* arow = (uint4*)(Abuf + row * 32);
        #pragma unroll
        for (int ch = 0; ch < 4; ++ch)
            arow[(ch + 4) ^ (row & 7)] = make_uint4(outv[ch * 4], outv[ch * 4 + 1],
                                                    outv[ch * 4 + 2], outv[ch * 4 + 3]);
    }
    __syncthreads();

    // MFMA + exact-f32 BN2 stats + bf16 y2t store
    {
        int wave = t >> 6, lane = t & 63;
        int wbase = wave * 32;
        int lr = lane & 15, lk = lane >> 4;
        bf16x8 afr[2][2], bfr[4][2];
        #pragma unroll
        for (int mt = 0; mt < 2; ++mt)
            #pragma unroll
            for (int kt = 0; kt < 2; ++kt) {
                int row = wbase + mt * 16 + lr;
                int ch = kt * 4 + lk;
                uint4 uu = ((const uint4*)(Abuf + row * 32))[ch ^ (row & 7)];
                afr[mt][kt] = __builtin_bit_cast(bf16x8, uu);
            }
        #pragma unroll
        for (int nt = 0; nt < 4; ++nt)
            #pragma unroll
            for (int kt = 0; kt < 2; ++kt) {
                int col = nt * 16 + lr;
                int ch = kt * 4 + lk;
                uint4 uu = ((const uint4*)(Bbuf + col * 32))[ch ^ (col & 7)];
                bfr[nt][kt] = __builtin_bit_cast(bf16x8, uu);
            }
        f32x4 acc[2][4];
        #pragma unroll
        for (int mt = 0; mt < 2; ++mt)
            #pragma unroll
            for (int nt = 0; nt < 4; ++nt) {
                acc[mt][nt] = (f32x4){0.f, 0.f, 0.f, 0.f};
                #pragma unroll
                for (int kt = 0; kt < 2; ++kt)
                    acc[mt][nt] = __builtin_amdgcn_mfma_f32_16x16x32_bf16(
                        afr[mt][kt], bfr[nt][kt], acc[mt][nt], 0, 0, 0);
            }
        float sa[4] = {0.f, 0.f, 0.f, 0.f}, sq[4] = {0.f, 0.f, 0.f, 0.f};
        #pragma unroll
        for (int mt = 0; mt < 2; ++mt)
            #pragma unroll
            for (int nt = 0; nt < 4; ++nt)
                #pragma unroll
                for (int e = 0; e < 4; ++e) {
                    float v = acc[mt][nt][e];
                    sa[nt] += v; sq[nt] += v * v;
                }
        #pragma unroll
        for (int nt = 0; nt < 4; ++nt) {
            sa[nt] += __shfl_xor(sa[nt], 16); sa[nt] += __shfl_xor(sa[nt], 32);
            sq[nt] += __shfl_xor(sq[nt], 16); sq[nt] += __shfl_xor(sq[nt], 32);
        }
        if (lane < 16) {
            #pragma unroll
            for (int nt = 0; nt < 4; ++nt) {
                atomicAdd(&accs[nt * 16 + lr], sa[nt]);
                atomicAdd(&accs[64 + nt * 16 + lr], sq[nt]);
            }
        }
        #pragma unroll
        for (int mt = 0; mt < 2; ++mt)
            #pragma unroll
            for (int nt = 0; nt < 4; ++nt) {
                int col = nt * 16 + lr;
                int w0 = (wbase + mt * 16 + lk * 4) >> 1;
                unsigned u0 = (unsigned)f2bf(acc[mt][nt][0]) | ((unsigned)f2bf(acc[mt][nt][1]) << 16);
                unsigned u1 = (unsigned)f2bf(acc[mt][nt][2]) | ((unsigned)f2bf(acc[mt][nt][3]) << 16);
                y2t[col * 64 + (w0 ^ (col & 31))] = u0;
                y2t[col * 64 + ((w0 + 1) ^ (col & 31))] = u1;
            }
    }
    __syncthreads();

    // segmented max over sorted rows
    {
        int c = t & 63, ck = t >> 6;
        int r0 = ck * 32;
        int cur_v = -2; float cur_m = 0.f;
        int hvv = -2; float hkk = 0.f; bool fd = false;
        for (int q = 0; q < 16; ++q) {
            unsigned u = y2t[c * 64 + (((r0 >> 1) + q) ^ (c & 31))];
            #pragma unroll
            for (int e = 0; e < 2; ++e) {
                int r = r0 + 2 * q + e;
                float d = bf2f((unsigned short)(e ? (u >> 16) : (u & 0xFFFF)));
                int v = vids[r];
                if (q == 0 && e == 0) { cur_v = v; cur_m = d; }
                else if (v == cur_v) cur_m = fmaxf(cur_m, d);
                else {
                    if (!fd) { hvv = cur_v; hkk = cur_m; fd = true; }
                    else if ((unsigned)cur_v < (unsigned)NVOX)
                        okeys[(size_t)cur_v * 64 + c] = fkey(cur_m);
                    cur_v = v; cur_m = d;
                }
            }
        }
        hv[ck][c] = fd ? hvv : cur_v; hk[ck][c] = fd ? hkk : cur_m;
        tv[ck][c] = cur_v; tk[ck][c] = cur_m; sgl[ck][c] = fd ? 0 : 1;
    }
    __syncthreads();
    if (t < 64) {
        int cv = hv[0][t]; float cm = hk[0][t]; bool fs = true;
        #pragma unroll
        for (int k2 = 0; k2 < 4; ++k2) {
            if (k2 > 0) {
                int nv = hv[k2][t]; float nm = hk[k2][t];
                if (nv == cv) cm = fmaxf(cm, nm);
                else { flush64(cv, cm, fs, t, okeys); cv = nv; cm = nm; fs = false; }
            }
            if (!sgl[k2][t]) {
                flush64(cv, cm, fs, t, okeys);
                cv = tv[k2][t]; cm = tk[k2][t]; fs = false;
            }
        }
        flush64(cv, cm, true, t, okeys);
    }
    if (t < 128) atomicAdd(&stats[128 + t], accs[t]);
}

__global__ void k_fin2(float* __restrict__ stats, const float* __restrict__ g2,
                       const float* __restrict__ b2) {
    int c = threadIdx.x;
    if (c >= 64) return;
    float invn = 1.0f / (float)NPTS;
    float mu = stats[128 + c] * invn;
    float var = stats[192 + c] * invn - mu * mu;
    float sc = rsqrtf(var + BN_EPS) * g2[c];
    stats[256 + c] = sc;
    stats[320 + c] = b2[c] - mu * sc;
}

__global__ void k_out(unsigned* __restrict__ okeys, const float* __restrict__ stats) {
    int idx = blockIdx.x * 256 + threadIdx.x;
    int c = idx & 63;
    float raw = funkey(okeys[idx]);
    float val = fmaxf(0.0f, fmaf(raw, stats[256 + c], stats[320 + c]));
    ((float*)okeys)[idx] = val;
}

extern "C" void kernel_launch(void* const* d_in, const int* in_sizes, int n_in,
                              void* d_out, int out_size, void* d_ws, size_t ws_size,
                              hipStream_t stream) {
    const float* xyz = (const float*)d_in[0];
    const float* pf  = (const float*)d_in[1];
    const float* w1  = (const float*)d_in[2];
    const float* g1  = (const float*)d_in[3];
    const float* b1  = (const float*)d_in[4];
    const float* w2  = (const float*)d_in[5];
    const float* g2  = (const float*)d_in[6];
    const float* b2  = (const float*)d_in[7];
    const int*   unq = (const int*)d_in[8];

    float4* spts     = (float4*)d_ws;                        // PAD float4 (24 MB)
    float4* vmeanv   = spts + PAD;                           // NVOX float4 (4 MB)
    int* svid        = (int*)(vmeanv + NVOX);                // PAD ints (6 MB)
    unsigned* xmraw  = (unsigned*)(svid + PAD);              // NVOX*32 f32-fkeys (32 MB)
    int* cntv        = (int*)(xmraw + (size_t)NVOX * 32);    // NVOX
    int* startv      = cntv + NVOX;                          // NVOX
    int* offv        = startv + NVOX;                        // NVOX
    int* bsum        = offv + NVOX;                          // 256
    float* stats     = (float*)(bsum + 256);                 // 1024

    unsigned* okeys = (unsigned*)d_out;

    hipMemsetAsync(cntv, 0, (size_t)NVOX * sizeof(int), stream);
    hipMemsetAsync(stats, 0, 1024 * sizeof(float), stream);
    hipMemsetAsync(svid + NPTS, 0xFF, (PAD - NPTS) * sizeof(int), stream);
    k_fill<<<NVOX * 64 / 256, 256, 0, stream>>>(okeys, KEY_NEG_INF);
    k_fill<<<NVOX * 32 / 256, 256, 0, stream>>>(xmraw, KEY_NEG_INF);

    k_hist<<<NB_PT, 256, 0, stream>>>(unq, cntv);
    k_scanA<<<256, 256, 0, stream>>>(cntv, startv, bsum);
    k_scanB<<<1, 256, 0, stream>>>(bsum);
    k_scanC<<<256, 256, 0, stream>>>(startv, offv, bsum);
    k_scatter2<<<NB_PT, 256, 0, stream>>>(xyz, pf, unq, offv, spts, svid);
    k_vmean2<<<4096, 256, 0, stream>>>(spts, cntv, startv, vmeanv);
    k_passA<<<NB_PT, 256, 0, stream>>>(spts, svid, vmeanv, w1, xmraw, stats);
    k_fin1<<<1, 64, 0, stream>>>(stats, g1, b1);
    k_l2<<<NB_L2, 256, 0, stream>>>(spts, svid, vmeanv, w1, xmraw, w2, stats, okeys);
    k_fin2<<<1, 64, 0, stream>>>(stats, g2, b2);
    k_out<<<NVOX * 64 / 256, 256, 0, stream>>>(okeys, stats);
}

// Round 5
// 484.850 us; speedup vs baseline: 1.6187x; 1.5879x over previous
//
#include <hip/hip_runtime.h>

#define NPTS 1500000
#define NVOX 262144
#define BN_EPS 1e-3f
#define PAD 1500160        // NB_PT*256 == NB_L2*128
#define NB_PT 5860
#define NB_L2 11720

typedef __attribute__((ext_vector_type(8))) short bf16x8;
typedef __attribute__((ext_vector_type(4))) float f32x4;

__device__ __forceinline__ unsigned fkey(float f) {
    unsigned u = __float_as_uint(f);
    return u ^ ((unsigned)(((int)u) >> 31) | 0x80000000u);
}
__device__ __forceinline__ float funkey(unsigned k) {
    unsigned u = (k & 0x80000000u) ? (k ^ 0x80000000u) : ~k;
    return __uint_as_float(u);
}
#define KEY_NEG_INF 0x007FFFFFu

__device__ __forceinline__ float bf2f(unsigned short h) {
    union { unsigned u; float f; } x; x.u = ((unsigned)h) << 16; return x.f;
}
__device__ __forceinline__ unsigned short f2bf(float f) {
    union { float f; unsigned u; } x; x.f = f;
    unsigned r = x.u + 0x7FFFu + ((x.u >> 16) & 1u);
    return (unsigned short)(r >> 16);
}

__device__ __forceinline__ void make_feat(float x, float y, float z, float w,
                                          float mx, float my, float mz, float* f) {
    const float VS = 0.32f;
    const float PMX = -74.88f, PMY = -74.88f, PMZ = -2.0f;
    f[0] = x; f[1] = y; f[2] = z; f[3] = w;
    f[4] = x - mx; f[5] = y - my; f[6] = z - mz;
    float cx = floorf((x - PMX) / VS);
    float cy = floorf((y - PMY) / VS);
    float cz = floorf((z - PMZ) / VS);
    f[7] = x - (cx * VS + 0.5f * VS + PMX);
    f[8] = y - (cy * VS + 0.5f * VS + PMY);
    f[9] = z - (cz * VS + 0.5f * VS + PMZ);
    f[10] = sqrtf(x * x + y * y + z * z);
}

__global__ void k_fill(unsigned* __restrict__ p, unsigned v) {
    p[(size_t)blockIdx.x * 256 + threadIdx.x] = v;
}

__global__ void k_hist(const int* __restrict__ unq, int* __restrict__ cntv) {
    int i = blockIdx.x * blockDim.x + threadIdx.x;
    if (i < NPTS) atomicAdd(&cntv[unq[i]], 1);
}

__global__ void k_scanA(const int* __restrict__ cntv, int* __restrict__ startv,
                        int* __restrict__ bsum) {
    __shared__ int lds[256];
    int t = threadIdx.x;
    int idx4 = blockIdx.x * 256 + t;
    int4 cv = ((const int4*)cntv)[idx4];
    int s0 = cv.x, s1 = s0 + cv.y, s2 = s1 + cv.z, T = s2 + cv.w;
    lds[t] = T;
    __syncthreads();
    for (int o = 1; o < 256; o <<= 1) {
        int v = (t >= o) ? lds[t - o] : 0;
        __syncthreads();
        lds[t] += v;
        __syncthreads();
    }
    int excl = lds[t] - T;
    int4 ov; ov.x = excl; ov.y = excl + s0; ov.z = excl + s1; ov.w = excl + s2;
    ((int4*)startv)[idx4] = ov;
    if (t == 255) bsum[blockIdx.x] = lds[255];
}

__global__ void k_scanB(int* __restrict__ bsum) {
    __shared__ int lds[256];
    int t = threadIdx.x;
    int b = bsum[t];
    lds[t] = b;
    __syncthreads();
    for (int o = 1; o < 256; o <<= 1) {
        int v = (t >= o) ? lds[t - o] : 0;
        __syncthreads();
        lds[t] += v;
        __syncthreads();
    }
    bsum[t] = lds[t] - b;
}

__global__ void k_scanC(int* __restrict__ startv, int* __restrict__ offv,
                        const int* __restrict__ bsum) {
    int t = threadIdx.x;
    int idx4 = blockIdx.x * 256 + t;
    int add = bsum[blockIdx.x];
    int4 v = ((int4*)startv)[idx4];
    v.x += add; v.y += add; v.z += add; v.w += add;
    ((int4*)startv)[idx4] = v;
    ((int4*)offv)[idx4] = v;
}

__global__ void k_scatter2(const float* __restrict__ xyz, const float* __restrict__ pf,
                           const int* __restrict__ unq, int* __restrict__ offv,
                           float4* __restrict__ spts, int* __restrict__ svid) {
    int i = blockIdx.x * blockDim.x + threadIdx.x;
    if (i >= NPTS) return;
    int v = unq[i];
    int pos = atomicAdd(&offv[v], 1);
    float4 p;
    p.x = xyz[3 * i + 0]; p.y = xyz[3 * i + 1]; p.z = xyz[3 * i + 2]; p.w = pf[i];
    spts[pos] = p;
    svid[pos] = v;
}

__global__ __launch_bounds__(256) void k_vmean2(
    const float4* __restrict__ spts, const int* __restrict__ cntv,
    const int* __restrict__ startv, float4* __restrict__ vmeanv) {
    int t = threadIdx.x;
    int wave = t >> 6, lane = t & 63;
    int vb = (blockIdx.x * 4 + wave) * 16;
    for (int u = 0; u < 16; ++u) {
        int v = vb + u;
        int cnt = cntv[v];
        if (cnt == 0) continue;
        int st = startv[v];
        float sx = 0, sy = 0, sz = 0;
        for (int j = lane; j < cnt; j += 64) {
            float4 p = spts[st + j];
            sx += p.x; sy += p.y; sz += p.z;
        }
        #pragma unroll
        for (int o = 32; o; o >>= 1) {
            sx += __shfl_xor(sx, o); sy += __shfl_xor(sy, o); sz += __shfl_xor(sz, o);
        }
        if (lane == 0) {
            float inv = 1.0f / (float)cnt;
            vmeanv[v] = make_float4(sx * inv, sy * inv, sz * inv, 0.f);
        }
    }
}

// prepack w2 into MFMA B-fragment layout: wfrag[(nt*2+kt)*64 + lane] (8 bf16 each)
__global__ void k_prep(const float* __restrict__ w2, uint4* __restrict__ wfrag) {
    int l = threadIdx.x;
    int lr = l & 15, lk = l >> 4;
    #pragma unroll
    for (int nt = 0; nt < 4; ++nt)
        #pragma unroll
        for (int kt = 0; kt < 2; ++kt) {
            int col = nt * 16 + lr;
            int kb = kt * 32 + lk * 8;
            unsigned u[4];
            #pragma unroll
            for (int j = 0; j < 4; ++j) {
                float a = w2[(kb + 2 * j) * 64 + col];
                float b = w2[(kb + 2 * j + 1) * 64 + col];
                u[j] = (unsigned)f2bf(a) | ((unsigned)f2bf(b) << 16);
            }
            wfrag[(nt * 2 + kt) * 64 + l] = make_uint4(u[0], u[1], u[2], u[3]);
        }
}

__device__ __forceinline__ void flush32(int v, float m, bool atom, int c,
                                        unsigned* __restrict__ xm) {
    if ((unsigned)v >= (unsigned)NVOX) return;
    if (atom) atomicMax(&xm[(size_t)v * 32 + c], fkey(m));
    else xm[(size_t)v * 32 + c] = fkey(m);
}
__device__ __forceinline__ void flush64(int v, float m, bool atom, int c,
                                        unsigned* __restrict__ ok) {
    if ((unsigned)v >= (unsigned)NVOX) return;
    if (atom) atomicMax(&ok[(size_t)v * 64 + c], fkey(m));
    else ok[(size_t)v * 64 + c] = fkey(m);
}

// passA: per-point layer-1 (f32) -> BN1 stats (spread partials) + per-voxel raw-y1 max
__global__ __launch_bounds__(256) void k_passA(
    const float4* __restrict__ spts, const int* __restrict__ svid,
    const float4* __restrict__ vmeanv, const float* __restrict__ w1,
    unsigned* __restrict__ xmraw, float* __restrict__ spart1) {
    __shared__ float ylds[256 * 32];
    __shared__ int vlds[256];
    __shared__ float accs[64];
    __shared__ int hv[8][32]; __shared__ float hk[8][32];
    __shared__ int tv[8][32]; __shared__ float tk[8][32];
    __shared__ unsigned char sgl[8][32];
    int t = threadIdx.x;
    if (t < 64) accs[t] = 0.f;
    long grow = (long)blockIdx.x * 256 + t;
    int vid = (grow < NPTS) ? svid[grow] : -1;
    vlds[t] = vid;
    float yv[32];
    #pragma unroll
    for (int c = 0; c < 32; ++c) yv[c] = 0.f;
    if (vid >= 0) {
        float4 p = spts[grow];
        float4 vm = vmeanv[vid];
        float f[11];
        make_feat(p.x, p.y, p.z, p.w, vm.x, vm.y, vm.z, f);
        #pragma unroll
        for (int k = 0; k < 11; ++k) {
            float fk = f[k];
            #pragma unroll
            for (int c = 0; c < 32; ++c) yv[c] = fmaf(fk, w1[k * 32 + c], yv[c]);
        }
    }
    f32x4* yr = (f32x4*)&ylds[t * 32];
    #pragma unroll
    for (int q = 0; q < 8; ++q) {
        f32x4 vv = {yv[4 * q], yv[4 * q + 1], yv[4 * q + 2], yv[4 * q + 3]};
        yr[q ^ (t & 7)] = vv;
    }
    __syncthreads();
    {
        int c = t & 31, ck = t >> 5;
        int cq = c >> 2, ce = c & 3;
        float sa = 0.f, sq = 0.f;
        int cur_v = -2; float cur_m = 0.f;
        int hvv = -2; float hkk = 0.f; bool fd = false;
        for (int s = 0; s < 32; ++s) {
            int r = ck * 32 + s;
            float y = ylds[r * 32 + 4 * (cq ^ (r & 7)) + ce];
            int v = vlds[r];
            sa += y; sq += y * y;
            if (s == 0) { cur_v = v; cur_m = y; }
            else if (v == cur_v) cur_m = fmaxf(cur_m, y);
            else {
                if (!fd) { hvv = cur_v; hkk = cur_m; fd = true; }
                else if ((unsigned)cur_v < (unsigned)NVOX)
                    xmraw[(size_t)cur_v * 32 + c] = fkey(cur_m);
                cur_v = v; cur_m = y;
            }
        }
        hv[ck][c] = fd ? hvv : cur_v; hk[ck][c] = fd ? hkk : cur_m;
        tv[ck][c] = cur_v; tk[ck][c] = cur_m; sgl[ck][c] = fd ? 0 : 1;
        atomicAdd(&accs[c], sa);
        atomicAdd(&accs[32 + c], sq);
    }
    __syncthreads();
    if (t < 32) {
        int cv = hv[0][t]; float cm = hk[0][t]; bool fs = true;
        #pragma unroll
        for (int k2 = 0; k2 < 8; ++k2) {
            if (k2 > 0) {
                int nv = hv[k2][t]; float nm = hk[k2][t];
                if (nv == cv) cm = fmaxf(cm, nm);
                else { flush32(cv, cm, fs, t, xmraw); cv = nv; cm = nm; fs = false; }
            }
            if (!sgl[k2][t]) {
                flush32(cv, cm, fs, t, xmraw);
                cv = tv[k2][t]; cm = tk[k2][t]; fs = false;
            }
        }
        flush32(cv, cm, true, t, xmraw);
    }
    if (t < 64) atomicAdd(&spart1[(blockIdx.x & 255) * 64 + t], accs[t]);
}

// reduce 256x64 partials -> BN1 affine coefficients
__global__ void k_fin1(const float* __restrict__ spart1, float* __restrict__ stats,
                       const float* __restrict__ g1, const float* __restrict__ b1) {
    __shared__ float cs[64];
    int t = threadIdx.x;
    float s = 0.f;
    for (int r = 0; r < 256; ++r) s += spart1[r * 64 + t];
    cs[t] = s;
    __syncthreads();
    if (t < 32) {
        float invn = 1.0f / (float)NPTS;
        float mu = cs[t] * invn;
        float var = cs[32 + t] * invn - mu * mu;
        float sc = rsqrtf(var + BN_EPS) * g1[t];
        stats[64 + t] = sc;
        stats[96 + t] = b1[t] - mu * sc;
    }
}

// k_l2: in-block z1 + gathered xm -> MFMA y2 -> segmented max + BN2 partials
__global__ __launch_bounds__(256) void k_l2(
    const float4* __restrict__ spts, const int* __restrict__ svid,
    const float4* __restrict__ vmeanv, const float* __restrict__ w1,
    const unsigned* __restrict__ xmraw, const uint4* __restrict__ wfrag,
    const float* __restrict__ stats, float* __restrict__ spart2,
    unsigned* __restrict__ okeys) {
    __shared__ unsigned Abuf[128 * 32];
    __shared__ unsigned y2t[64 * 64];       // bf16 pairs [col][row/2] swizzled
    __shared__ int vids[128];
    __shared__ float accs[128];
    __shared__ int hv[4][64]; __shared__ float hk[4][64];
    __shared__ int tv[4][64]; __shared__ float tk[4][64];
    __shared__ unsigned char sgl[4][64];
    int t = threadIdx.x;
    int lane = t & 63;
    long brow = (long)blockIdx.x * 128;

    // B fragments direct from prepacked global (L2 broadcast)
    uint4 bw[8];
    #pragma unroll
    for (int q = 0; q < 8; ++q) bw[q] = wfrag[q * 64 + lane];

    if (t < 128) accs[t] = 0.f;

    // A = [z1 | z(xm)] bf16: threads 0-127 compute z1 rows, 128-255 gather xm rows
    if (t < 128) {
        int row = t;
        long grow = brow + row;
        int vid = (grow < NPTS) ? svid[grow] : -1;
        unsigned outv[16];
        if (vid >= 0) {
            float4 p = spts[grow];
            float4 vm = vmeanv[vid];
            float f[11];
            make_feat(p.x, p.y, p.z, p.w, vm.x, vm.y, vm.z, f);
            float yv[32];
            #pragma unroll
            for (int c = 0; c < 32; ++c) yv[c] = 0.f;
            #pragma unroll
            for (int k = 0; k < 11; ++k) {
                float fk = f[k];
                #pragma unroll
                for (int c = 0; c < 32; ++c) yv[c] = fmaf(fk, w1[k * 32 + c], yv[c]);
            }
            #pragma unroll
            for (int q = 0; q < 16; ++q) {
                float z0 = fmaxf(0.f, fmaf(yv[2 * q], stats[64 + 2 * q], stats[96 + 2 * q]));
                float z1 = fmaxf(0.f, fmaf(yv[2 * q + 1], stats[64 + 2 * q + 1], stats[96 + 2 * q + 1]));
                outv[q] = (unsigned)f2bf(z0) | ((unsigned)f2bf(z1) << 16);
            }
        } else {
            #pragma unroll
            for (int q = 0; q < 16; ++q) outv[q] = 0u;
        }
        uint4* arow = (uint4*)(Abuf + row * 32);
        #pragma unroll
        for (int ch = 0; ch < 4; ++ch)
            arow[ch ^ (row & 7)] = make_uint4(outv[ch * 4], outv[ch * 4 + 1],
                                              outv[ch * 4 + 2], outv[ch * 4 + 3]);
    } else {
        int row = t - 128;
        long grow = brow + row;
        int vid = (grow < NPTS) ? svid[grow] : -1;
        vids[row] = vid;
        unsigned outv[16];
        if (vid >= 0) {
            const uint4* src = (const uint4*)(xmraw + (size_t)vid * 32);
            #pragma unroll
            for (int q = 0; q < 8; ++q) {
                uint4 uu = src[q];
                unsigned w4[4] = {uu.x, uu.y, uu.z, uu.w};
                #pragma unroll
                for (int e = 0; e < 2; ++e) {
                    int c0 = q * 4 + 2 * e;
                    float z0 = fmaxf(0.f, fmaf(funkey(w4[2 * e]), stats[64 + c0], stats[96 + c0]));
                    float z1 = fmaxf(0.f, fmaf(funkey(w4[2 * e + 1]), stats[64 + c0 + 1], stats[96 + c0 + 1]));
                    outv[q * 2 + e] = (unsigned)f2bf(z0) | ((unsigned)f2bf(z1) << 16);
                }
            }
        } else {
            #pragma unroll
            for (int q = 0; q < 16; ++q) outv[q] = 0u;
        }
        uint4* arow = (uint4*)(Abuf + row * 32);
        #pragma unroll
        for (int ch = 0; ch < 4; ++ch)
            arow[(ch + 4) ^ (row & 7)] = make_uint4(outv[ch * 4], outv[ch * 4 + 1],
                                                    outv[ch * 4 + 2], outv[ch * 4 + 3]);
    }
    __syncthreads();

    // MFMA + exact-f32 BN2 partials + bf16 y2t store
    {
        int wave = t >> 6;
        int wbase = wave * 32;
        int lr = lane & 15, lk = lane >> 4;
        bf16x8 afr[2][2], bfr[4][2];
        #pragma unroll
        for (int mt = 0; mt < 2; ++mt)
            #pragma unroll
            for (int kt = 0; kt < 2; ++kt) {
                int row = wbase + mt * 16 + lr;
                int ch = kt * 4 + lk;
                uint4 uu = ((const uint4*)(Abuf + row * 32))[ch ^ (row & 7)];
                afr[mt][kt] = __builtin_bit_cast(bf16x8, uu);
            }
        #pragma unroll
        for (int nt = 0; nt < 4; ++nt)
            #pragma unroll
            for (int kt = 0; kt < 2; ++kt)
                bfr[nt][kt] = __builtin_bit_cast(bf16x8, bw[nt * 2 + kt]);
        f32x4 acc[2][4];
        #pragma unroll
        for (int mt = 0; mt < 2; ++mt)
            #pragma unroll
            for (int nt = 0; nt < 4; ++nt) {
                acc[mt][nt] = (f32x4){0.f, 0.f, 0.f, 0.f};
                #pragma unroll
                for (int kt = 0; kt < 2; ++kt)
                    acc[mt][nt] = __builtin_amdgcn_mfma_f32_16x16x32_bf16(
                        afr[mt][kt], bfr[nt][kt], acc[mt][nt], 0, 0, 0);
            }
        float sa[4] = {0.f, 0.f, 0.f, 0.f}, sq[4] = {0.f, 0.f, 0.f, 0.f};
        #pragma unroll
        for (int mt = 0; mt < 2; ++mt)
            #pragma unroll
            for (int nt = 0; nt < 4; ++nt)
                #pragma unroll
                for (int e = 0; e < 4; ++e) {
                    float v = acc[mt][nt][e];
                    sa[nt] += v; sq[nt] += v * v;
                }
        #pragma unroll
        for (int nt = 0; nt < 4; ++nt) {
            sa[nt] += __shfl_xor(sa[nt], 16); sa[nt] += __shfl_xor(sa[nt], 32);
            sq[nt] += __shfl_xor(sq[nt], 16); sq[nt] += __shfl_xor(sq[nt], 32);
        }
        if ((lane & 48) == 0) {
            int lr2 = lane & 15;
            #pragma unroll
            for (int nt = 0; nt < 4; ++nt) {
                atomicAdd(&accs[nt * 16 + lr2], sa[nt]);
                atomicAdd(&accs[64 + nt * 16 + lr2], sq[nt]);
            }
        }
        #pragma unroll
        for (int mt = 0; mt < 2; ++mt)
            #pragma unroll
            for (int nt = 0; nt < 4; ++nt) {
                int col = nt * 16 + lr;
                int w0 = (wbase + mt * 16 + lk * 4) >> 1;
                unsigned u0 = (unsigned)f2bf(acc[mt][nt][0]) | ((unsigned)f2bf(acc[mt][nt][1]) << 16);
                unsigned u1 = (unsigned)f2bf(acc[mt][nt][2]) | ((unsigned)f2bf(acc[mt][nt][3]) << 16);
                y2t[col * 64 + (w0 ^ (col & 31))] = u0;
                y2t[col * 64 + ((w0 + 1) ^ (col & 31))] = u1;
            }
    }
    __syncthreads();

    // segmented max over sorted rows
    {
        int c = t & 63, ck = t >> 6;
        int r0 = ck * 32;
        int cur_v = -2; float cur_m = 0.f;
        int hvv = -2; float hkk = 0.f; bool fd = false;
        for (int q = 0; q < 16; ++q) {
            unsigned u = y2t[c * 64 + (((r0 >> 1) + q) ^ (c & 31))];
            #pragma unroll
            for (int e = 0; e < 2; ++e) {
                int r = r0 + 2 * q + e;
                float d = bf2f((unsigned short)(e ? (u >> 16) : (u & 0xFFFF)));
                int v = vids[r];
                if (q == 0 && e == 0) { cur_v = v; cur_m = d; }
                else if (v == cur_v) cur_m = fmaxf(cur_m, d);
                else {
                    if (!fd) { hvv = cur_v; hkk = cur_m; fd = true; }
                    else if ((unsigned)cur_v < (unsigned)NVOX)
                        okeys[(size_t)cur_v * 64 + c] = fkey(cur_m);
                    cur_v = v; cur_m = d;
                }
            }
        }
        hv[ck][c] = fd ? hvv : cur_v; hk[ck][c] = fd ? hkk : cur_m;
        tv[ck][c] = cur_v; tk[ck][c] = cur_m; sgl[ck][c] = fd ? 0 : 1;
    }
    __syncthreads();
    if (t < 64) {
        int cv = hv[0][t]; float cm = hk[0][t]; bool fs = true;
        #pragma unroll
        for (int k2 = 0; k2 < 4; ++k2) {
            if (k2 > 0) {
                int nv = hv[k2][t]; float nm = hk[k2][t];
                if (nv == cv) cm = fmaxf(cm, nm);
                else { flush64(cv, cm, fs, t, okeys); cv = nv; cm = nm; fs = false; }
            }
            if (!sgl[k2][t]) {
                flush64(cv, cm, fs, t, okeys);
                cv = tv[k2][t]; cm = tk[k2][t]; fs = false;
            }
        }
        flush64(cv, cm, true, t, okeys);
    }
    if (t < 128) atomicAdd(&spart2[(blockIdx.x & 255) * 128 + t], accs[t]);
}

// reduce 256x128 partials -> BN2 affine coefficients
__global__ void k_fin2(const float* __restrict__ spart2, float* __restrict__ stats,
                       const float* __restrict__ g2, const float* __restrict__ b2) {
    __shared__ float cs[128];
    int t = threadIdx.x;
    float s = 0.f;
    for (int r = 0; r < 256; ++r) s += spart2[r * 128 + t];
    cs[t] = s;
    __syncthreads();
    if (t < 64) {
        float invn = 1.0f / (float)NPTS;
        float mu = cs[t] * invn;
        float var = cs[64 + t] * invn - mu * mu;
        float sc = rsqrtf(var + BN_EPS) * g2[t];
        stats[256 + t] = sc;
        stats[320 + t] = b2[t] - mu * sc;
    }
}

__global__ void k_out(unsigned* __restrict__ okeys, const float* __restrict__ stats) {
    int idx = blockIdx.x * 256 + threadIdx.x;
    int c = idx & 63;
    float raw = funkey(okeys[idx]);
    float val = fmaxf(0.0f, fmaf(raw, stats[256 + c], stats[320 + c]));
    ((float*)okeys)[idx] = val;
}

extern "C" void kernel_launch(void* const* d_in, const int* in_sizes, int n_in,
                              void* d_out, int out_size, void* d_ws, size_t ws_size,
                              hipStream_t stream) {
    const float* xyz = (const float*)d_in[0];
    const float* pf  = (const float*)d_in[1];
    const float* w1  = (const float*)d_in[2];
    const float* g1  = (const float*)d_in[3];
    const float* b1  = (const float*)d_in[4];
    const float* w2  = (const float*)d_in[5];
    const float* g2  = (const float*)d_in[6];
    const float* b2  = (const float*)d_in[7];
    const int*   unq = (const int*)d_in[8];

    float4* spts     = (float4*)d_ws;                        // PAD float4 (24 MB)
    float4* vmeanv   = spts + PAD;                           // NVOX float4 (4 MB)
    int* svid        = (int*)(vmeanv + NVOX);                // PAD ints (6 MB)
    unsigned* xmraw  = (unsigned*)(svid + PAD);              // NVOX*32 f32-fkeys (32 MB)
    int* cntv        = (int*)(xmraw + (size_t)NVOX * 32);    // NVOX
    int* startv      = cntv + NVOX;                          // NVOX
    int* offv        = startv + NVOX;                        // NVOX
    int* bsum        = offv + NVOX;                          // 256
    float* stats     = (float*)(bsum + 256);                 // 1024
    float* spart1    = stats + 1024;                         // 256*64
    float* spart2    = spart1 + 256 * 64;                    // 256*128
    uint4* wfrag     = (uint4*)(spart2 + 256 * 128);         // 8*64 uint4

    unsigned* okeys = (unsigned*)d_out;

    hipMemsetAsync(cntv, 0, (size_t)NVOX * sizeof(int), stream);
    hipMemsetAsync(stats, 0, (size_t)(1024 + 256 * 64 + 256 * 128) * sizeof(float), stream);
    hipMemsetAsync(svid + NPTS, 0xFF, (PAD - NPTS) * sizeof(int), stream);
    k_fill<<<NVOX * 64 / 256, 256, 0, stream>>>(okeys, KEY_NEG_INF);
    k_fill<<<NVOX * 32 / 256, 256, 0, stream>>>(xmraw, KEY_NEG_INF);
    k_prep<<<1, 64, 0, stream>>>(w2, wfrag);

    k_hist<<<NB_PT, 256, 0, stream>>>(unq, cntv);
    k_scanA<<<256, 256, 0, stream>>>(cntv, startv, bsum);
    k_scanB<<<1, 256, 0, stream>>>(bsum);
    k_scanC<<<256, 256, 0, stream>>>(startv, offv, bsum);
    k_scatter2<<<NB_PT, 256, 0, stream>>>(xyz, pf, unq, offv, spts, svid);
    k_vmean2<<<4096, 256, 0, stream>>>(spts, cntv, startv, vmeanv);
    k_passA<<<NB_PT, 256, 0, stream>>>(spts, svid, vmeanv, w1, xmraw, spart1);
    k_fin1<<<1, 64, 0, stream>>>(spart1, stats, g1, b1);
    k_l2<<<NB_L2, 256, 0, stream>>>(spts, svid, vmeanv, w1, xmraw, wfrag, stats,
                                    spart2, okeys);
    k_fin2<<<1, 128, 0, stream>>>(spart2, stats, g2, b2);
    k_out<<<NVOX * 64 / 256, 256, 0, stream>>>(okeys, stats);
}

// Round 6
// 460.711 us; speedup vs baseline: 1.7035x; 1.0524x over previous
//
#include <hip/hip_runtime.h>

#define NPTS 1500000
#define NVOX 262144
#define BN_EPS 1e-3f
#define PAD 1500160        // NB_PT*256 == NB_L2*128
#define NB_PT 5860
#define NB_L2 11720

typedef __attribute__((ext_vector_type(8))) short bf16x8;
typedef __attribute__((ext_vector_type(4))) float f32x4;

__device__ __forceinline__ unsigned fkey(float f) {
    unsigned u = __float_as_uint(f);
    return u ^ ((unsigned)(((int)u) >> 31) | 0x80000000u);
}
__device__ __forceinline__ float funkey(unsigned k) {
    unsigned u = (k & 0x80000000u) ? (k ^ 0x80000000u) : ~k;
    return __uint_as_float(u);
}
#define KEY_NEG_INF 0x007FFFFFu

__device__ __forceinline__ float bf2f(unsigned short h) {
    union { unsigned u; float f; } x; x.u = ((unsigned)h) << 16; return x.f;
}
__device__ __forceinline__ unsigned short f2bf(float f) {
    union { float f; unsigned u; } x; x.f = f;
    unsigned r = x.u + 0x7FFFu + ((x.u >> 16) & 1u);
    return (unsigned short)(r >> 16);
}

__device__ __forceinline__ void make_feat(float x, float y, float z, float w,
                                          float mx, float my, float mz, float* f) {
    const float VS = 0.32f;
    const float PMX = -74.88f, PMY = -74.88f, PMZ = -2.0f;
    f[0] = x; f[1] = y; f[2] = z; f[3] = w;
    f[4] = x - mx; f[5] = y - my; f[6] = z - mz;
    float cx = floorf((x - PMX) / VS);
    float cy = floorf((y - PMY) / VS);
    float cz = floorf((z - PMZ) / VS);
    f[7] = x - (cx * VS + 0.5f * VS + PMX);
    f[8] = y - (cy * VS + 0.5f * VS + PMY);
    f[9] = z - (cz * VS + 0.5f * VS + PMZ);
    f[10] = sqrtf(x * x + y * y + z * z);
}

// one kernel: all fills/zeros + w2 frag prepack + svid pad
__global__ void k_init(unsigned* __restrict__ okeys, unsigned* __restrict__ xmraw,
                       int* __restrict__ cntv, float* __restrict__ zf,
                       int* __restrict__ svid, const float* __restrict__ w2,
                       uint4* __restrict__ wfrag) {
    long t0 = (long)blockIdx.x * 256 + threadIdx.x;
    long st = (long)gridDim.x * 256;
    uint4 kneg = make_uint4(KEY_NEG_INF, KEY_NEG_INF, KEY_NEG_INF, KEY_NEG_INF);
    for (long i = t0; i < (long)NVOX * 16; i += st) ((uint4*)okeys)[i] = kneg;
    for (long i = t0; i < (long)NVOX * 8; i += st) ((uint4*)xmraw)[i] = kneg;
    for (long i = t0; i < NVOX / 4; i += st) ((int4*)cntv)[i] = make_int4(0, 0, 0, 0);
    for (long i = t0; i < (1024 + 256 * 64 + 256 * 128) / 4; i += st)
        ((float4*)zf)[i] = make_float4(0.f, 0.f, 0.f, 0.f);
    if (t0 < PAD - NPTS) svid[NPTS + t0] = -1;
    if (blockIdx.x == 0 && threadIdx.x < 64) {
        int l = threadIdx.x;
        int lr = l & 15, lk = l >> 4;
        #pragma unroll
        for (int nt = 0; nt < 4; ++nt)
            #pragma unroll
            for (int kt = 0; kt < 2; ++kt) {
                int col = nt * 16 + lr;
                int kb = kt * 32 + lk * 8;
                unsigned u[4];
                #pragma unroll
                for (int j = 0; j < 4; ++j) {
                    float a = w2[(kb + 2 * j) * 64 + col];
                    float b = w2[(kb + 2 * j + 1) * 64 + col];
                    u[j] = (unsigned)f2bf(a) | ((unsigned)f2bf(b) << 16);
                }
                wfrag[(nt * 2 + kt) * 64 + l] = make_uint4(u[0], u[1], u[2], u[3]);
            }
    }
}

__global__ void k_hist(const int* __restrict__ unq, int* __restrict__ cntv) {
    int i = blockIdx.x * blockDim.x + threadIdx.x;
    if (i < NPTS) atomicAdd(&cntv[unq[i]], 1);
}

__global__ void k_scanA(const int* __restrict__ cntv, int* __restrict__ startv,
                        int* __restrict__ bsum) {
    __shared__ int lds[256];
    int t = threadIdx.x;
    int idx4 = blockIdx.x * 256 + t;
    int4 cv = ((const int4*)cntv)[idx4];
    int s0 = cv.x, s1 = s0 + cv.y, s2 = s1 + cv.z, T = s2 + cv.w;
    lds[t] = T;
    __syncthreads();
    for (int o = 1; o < 256; o <<= 1) {
        int v = (t >= o) ? lds[t - o] : 0;
        __syncthreads();
        lds[t] += v;
        __syncthreads();
    }
    int excl = lds[t] - T;
    int4 ov; ov.x = excl; ov.y = excl + s0; ov.z = excl + s1; ov.w = excl + s2;
    ((int4*)startv)[idx4] = ov;
    if (t == 255) bsum[blockIdx.x] = lds[255];
}

__global__ void k_scanB(int* __restrict__ bsum) {
    __shared__ int lds[256];
    int t = threadIdx.x;
    int b = bsum[t];
    lds[t] = b;
    __syncthreads();
    for (int o = 1; o < 256; o <<= 1) {
        int v = (t >= o) ? lds[t - o] : 0;
        __syncthreads();
        lds[t] += v;
        __syncthreads();
    }
    bsum[t] = lds[t] - b;
}

__global__ void k_scanC(int* __restrict__ startv, int* __restrict__ offv,
                        const int* __restrict__ bsum) {
    int t = threadIdx.x;
    int idx4 = blockIdx.x * 256 + t;
    int add = bsum[blockIdx.x];
    int4 v = ((int4*)startv)[idx4];
    v.x += add; v.y += add; v.z += add; v.w += add;
    ((int4*)startv)[idx4] = v;
    ((int4*)offv)[idx4] = v;
}

__global__ void k_scatter2(const float* __restrict__ xyz, const float* __restrict__ pf,
                           const int* __restrict__ unq, int* __restrict__ offv,
                           float4* __restrict__ spts, int* __restrict__ svid) {
    int i = blockIdx.x * blockDim.x + threadIdx.x;
    if (i >= NPTS) return;
    int v = unq[i];
    int pos = atomicAdd(&offv[v], 1);
    float4 p;
    p.x = xyz[3 * i + 0]; p.y = xyz[3 * i + 1]; p.z = xyz[3 * i + 2]; p.w = pf[i];
    spts[pos] = p;
    svid[pos] = v;
}

// thread-per-voxel mean
__global__ void k_vmean2(const float4* __restrict__ spts, const int* __restrict__ cntv,
                         const int* __restrict__ startv, float4* __restrict__ vmeanv) {
    int v = blockIdx.x * 256 + threadIdx.x;
    int cnt = cntv[v];
    if (!cnt) return;
    int st = startv[v];
    float sx = 0, sy = 0, sz = 0;
    for (int j = 0; j < cnt; ++j) {
        float4 p = spts[st + j];
        sx += p.x; sy += p.y; sz += p.z;
    }
    float inv = 1.0f / (float)cnt;
    vmeanv[v] = make_float4(sx * inv, sy * inv, sz * inv, 0.f);
}

__device__ __forceinline__ void flush32(int v, float m, bool atom, int c,
                                        unsigned* __restrict__ xm) {
    if ((unsigned)v >= (unsigned)NVOX) return;
    if (atom) atomicMax(&xm[(size_t)v * 32 + c], fkey(m));
    else xm[(size_t)v * 32 + c] = fkey(m);
}
__device__ __forceinline__ void flush64(int v, float m, bool atom, int c,
                                        unsigned* __restrict__ ok) {
    if ((unsigned)v >= (unsigned)NVOX) return;
    if (atom) atomicMax(&ok[(size_t)v * 64 + c], fkey(m));
    else ok[(size_t)v * 64 + c] = fkey(m);
}

// passA: per-point layer-1 (f32) -> BN1 partials + per-voxel raw-y1 max
__global__ __launch_bounds__(256) void k_passA(
    const float4* __restrict__ spts, const int* __restrict__ svid,
    const float4* __restrict__ vmeanv, const float* __restrict__ w1,
    unsigned* __restrict__ xmraw, float* __restrict__ spart1) {
    __shared__ float ylds[256 * 32];
    __shared__ int vlds[256];
    __shared__ float accs[64];
    __shared__ int hv[8][32]; __shared__ float hk[8][32];
    __shared__ int tv[8][32]; __shared__ float tk[8][32];
    __shared__ unsigned char sgl[8][32];
    int t = threadIdx.x;
    if (t < 64) accs[t] = 0.f;
    long grow = (long)blockIdx.x * 256 + t;
    int vid = (grow < NPTS) ? svid[grow] : -1;
    vlds[t] = vid;
    float yv[32];
    #pragma unroll
    for (int c = 0; c < 32; ++c) yv[c] = 0.f;
    if (vid >= 0) {
        float4 p = spts[grow];
        float4 vm = vmeanv[vid];
        float f[11];
        make_feat(p.x, p.y, p.z, p.w, vm.x, vm.y, vm.z, f);
        #pragma unroll
        for (int k = 0; k < 11; ++k) {
            float fk = f[k];
            #pragma unroll
            for (int c = 0; c < 32; ++c) yv[c] = fmaf(fk, w1[k * 32 + c], yv[c]);
        }
    }
    f32x4* yr = (f32x4*)&ylds[t * 32];
    #pragma unroll
    for (int q = 0; q < 8; ++q) {
        f32x4 vv = {yv[4 * q], yv[4 * q + 1], yv[4 * q + 2], yv[4 * q + 3]};
        yr[q ^ (t & 7)] = vv;
    }
    __syncthreads();
    {
        int c = t & 31, ck = t >> 5;
        int cq = c >> 2, ce = c & 3;
        float sa = 0.f, sq = 0.f;
        int cur_v = -2; float cur_m = 0.f;
        int hvv = -2; float hkk = 0.f; bool fd = false;
        for (int s = 0; s < 32; ++s) {
            int r = ck * 32 + s;
            float y = ylds[r * 32 + 4 * (cq ^ (r & 7)) + ce];
            int v = vlds[r];
            sa += y; sq += y * y;
            if (s == 0) { cur_v = v; cur_m = y; }
            else if (v == cur_v) cur_m = fmaxf(cur_m, y);
            else {
                if (!fd) { hvv = cur_v; hkk = cur_m; fd = true; }
                else if ((unsigned)cur_v < (unsigned)NVOX)
                    xmraw[(size_t)cur_v * 32 + c] = fkey(cur_m);
                cur_v = v; cur_m = y;
            }
        }
        hv[ck][c] = fd ? hvv : cur_v; hk[ck][c] = fd ? hkk : cur_m;
        tv[ck][c] = cur_v; tk[ck][c] = cur_m; sgl[ck][c] = fd ? 0 : 1;
        atomicAdd(&accs[c], sa);
        atomicAdd(&accs[32 + c], sq);
    }
    __syncthreads();
    if (t < 32) {
        int cv = hv[0][t]; float cm = hk[0][t]; bool fs = true;
        #pragma unroll
        for (int k2 = 0; k2 < 8; ++k2) {
            if (k2 > 0) {
                int nv = hv[k2][t]; float nm = hk[k2][t];
                if (nv == cv) cm = fmaxf(cm, nm);
                else { flush32(cv, cm, fs, t, xmraw); cv = nv; cm = nm; fs = false; }
            }
            if (!sgl[k2][t]) {
                flush32(cv, cm, fs, t, xmraw);
                cv = tv[k2][t]; cm = tk[k2][t]; fs = false;
            }
        }
        flush32(cv, cm, true, t, xmraw);
    }
    if (t < 64) atomicAdd(&spart1[(blockIdx.x & 255) * 64 + t], accs[t]);
}

__global__ void k_fin1(const float* __restrict__ spart1, float* __restrict__ stats,
                       const float* __restrict__ g1, const float* __restrict__ b1) {
    __shared__ float cs[64];
    int t = threadIdx.x;
    float s = 0.f;
    for (int r = 0; r < 256; ++r) s += spart1[r * 64 + t];
    cs[t] = s;
    __syncthreads();
    if (t < 32) {
        float invn = 1.0f / (float)NPTS;
        float mu = cs[t] * invn;
        float var = cs[32 + t] * invn - mu * mu;
        float sc = rsqrtf(var + BN_EPS) * g1[t];
        stats[64 + t] = sc;
        stats[96 + t] = b1[t] - mu * sc;
    }
}

// k_l2 v3: per-wave independent; per-lane z1 recompute (8 ch) + xm gather ->
// MFMA -> per-wave segmented max + BN2 partials. ONE barrier.
__global__ __launch_bounds__(256) void k_l2(
    const float4* __restrict__ spts, const int* __restrict__ svid,
    const float4* __restrict__ vmeanv, const float* __restrict__ w1,
    const unsigned* __restrict__ xmraw, const uint4* __restrict__ wfrag,
    const float* __restrict__ stats, float* __restrict__ spart2,
    unsigned* __restrict__ okeys) {
    __shared__ unsigned y2t[64 * 64];
    __shared__ float wsums[4][128];
    __shared__ int hv[4][64]; __shared__ float hk[4][64];
    __shared__ int tv[4][64]; __shared__ float tk[4][64];
    __shared__ unsigned char sgl[4][64];

    int t = threadIdx.x;
    int lane = t & 63, wave = t >> 6;
    int lr = lane & 15, lk = lane >> 4;
    int wbase = wave * 32;
    long brow = (long)blockIdx.x * 128;

    // BN1 coeffs for this lane's 8 channels (lk*8..+7)
    float sc1[8], sh1[8];
    {
        float4 a0 = ((const float4*)(stats + 64))[lk * 2];
        float4 a1 = ((const float4*)(stats + 64))[lk * 2 + 1];
        float4 b0 = ((const float4*)(stats + 96))[lk * 2];
        float4 b1_ = ((const float4*)(stats + 96))[lk * 2 + 1];
        sc1[0] = a0.x; sc1[1] = a0.y; sc1[2] = a0.z; sc1[3] = a0.w;
        sc1[4] = a1.x; sc1[5] = a1.y; sc1[6] = a1.z; sc1[7] = a1.w;
        sh1[0] = b0.x; sh1[1] = b0.y; sh1[2] = b0.z; sh1[3] = b0.w;
        sh1[4] = b1_.x; sh1[5] = b1_.y; sh1[6] = b1_.z; sh1[7] = b1_.w;
    }
    // voxel ids for this wave's 32 rows (lanes 0-31 hold them)
    int vid_l = svid[brow + wbase + (lane & 31)];

    // B fragments from prepacked global
    uint4 bw[8];
    #pragma unroll
    for (int q = 0; q < 8; ++q) bw[q] = wfrag[q * 64 + lane];

    // A fragments: z1 recompute (f32) + xm gather, 8 channels per lane
    bf16x8 afr[2][2];
    #pragma unroll
    for (int mt = 0; mt < 2; ++mt) {
        int riw = mt * 16 + lr;
        int vid = __shfl(vid_l, riw);
        long grow = brow + wbase + riw;
        unsigned packz[4], packx[4];
        if (vid >= 0) {
            float4 p = spts[grow];
            float4 vm = vmeanv[vid];
            float f[11];
            make_feat(p.x, p.y, p.z, p.w, vm.x, vm.y, vm.z, f);
            float yv[8];
            #pragma unroll
            for (int j = 0; j < 8; ++j) yv[j] = 0.f;
            const float4* w1f = (const float4*)w1;
            #pragma unroll
            for (int k = 0; k < 11; ++k) {
                float4 wa = w1f[k * 8 + lk * 2];
                float4 wb = w1f[k * 8 + lk * 2 + 1];
                float fk = f[k];
                yv[0] = fmaf(fk, wa.x, yv[0]); yv[1] = fmaf(fk, wa.y, yv[1]);
                yv[2] = fmaf(fk, wa.z, yv[2]); yv[3] = fmaf(fk, wa.w, yv[3]);
                yv[4] = fmaf(fk, wb.x, yv[4]); yv[5] = fmaf(fk, wb.y, yv[5]);
                yv[6] = fmaf(fk, wb.z, yv[6]); yv[7] = fmaf(fk, wb.w, yv[7]);
            }
            const uint4* xr = (const uint4*)(xmraw + (size_t)vid * 32);
            uint4 x0 = xr[lk * 2], x1 = xr[lk * 2 + 1];
            float xs[8] = {funkey(x0.x), funkey(x0.y), funkey(x0.z), funkey(x0.w),
                           funkey(x1.x), funkey(x1.y), funkey(x1.z), funkey(x1.w)};
            #pragma unroll
            for (int e = 0; e < 4; ++e) {
                float z0 = fmaxf(0.f, fmaf(yv[2 * e], sc1[2 * e], sh1[2 * e]));
                float z1 = fmaxf(0.f, fmaf(yv[2 * e + 1], sc1[2 * e + 1], sh1[2 * e + 1]));
                packz[e] = (unsigned)f2bf(z0) | ((unsigned)f2bf(z1) << 16);
                float q0 = fmaxf(0.f, fmaf(xs[2 * e], sc1[2 * e], sh1[2 * e]));
                float q1 = fmaxf(0.f, fmaf(xs[2 * e + 1], sc1[2 * e + 1], sh1[2 * e + 1]));
                packx[e] = (unsigned)f2bf(q0) | ((unsigned)f2bf(q1) << 16);
            }
        } else {
            #pragma unroll
            for (int e = 0; e < 4; ++e) { packz[e] = 0u; packx[e] = 0u; }
        }
        afr[mt][0] = __builtin_bit_cast(bf16x8, make_uint4(packz[0], packz[1], packz[2], packz[3]));
        afr[mt][1] = __builtin_bit_cast(bf16x8, make_uint4(packx[0], packx[1], packx[2], packx[3]));
    }

    // MFMA
    f32x4 acc[2][4];
    #pragma unroll
    for (int mt = 0; mt < 2; ++mt)
        #pragma unroll
        for (int nt = 0; nt < 4; ++nt) {
            acc[mt][nt] = (f32x4){0.f, 0.f, 0.f, 0.f};
            #pragma unroll
            for (int kt = 0; kt < 2; ++kt)
                acc[mt][nt] = __builtin_amdgcn_mfma_f32_16x16x32_bf16(
                    afr[mt][kt], __builtin_bit_cast(bf16x8, bw[nt * 2 + kt]),
                    acc[mt][nt], 0, 0, 0);
        }

    // BN2 partials (exact f32)
    {
        float sa[4] = {0.f, 0.f, 0.f, 0.f}, sq[4] = {0.f, 0.f, 0.f, 0.f};
        #pragma unroll
        for (int mt = 0; mt < 2; ++mt)
            #pragma unroll
            for (int nt = 0; nt < 4; ++nt)
                #pragma unroll
                for (int e = 0; e < 4; ++e) {
                    float v = acc[mt][nt][e];
                    sa[nt] += v; sq[nt] += v * v;
                }
        #pragma unroll
        for (int nt = 0; nt < 4; ++nt) {
            sa[nt] += __shfl_xor(sa[nt], 16); sa[nt] += __shfl_xor(sa[nt], 32);
            sq[nt] += __shfl_xor(sq[nt], 16); sq[nt] += __shfl_xor(sq[nt], 32);
        }
        if (lk == 0) {
            #pragma unroll
            for (int nt = 0; nt < 4; ++nt) {
                wsums[wave][nt * 16 + lr] = sa[nt];
                wsums[wave][64 + nt * 16 + lr] = sq[nt];
            }
        }
    }

    // y2t store (bf16 pairs, swizzled) — own rows only
    #pragma unroll
    for (int mt = 0; mt < 2; ++mt)
        #pragma unroll
        for (int nt = 0; nt < 4; ++nt) {
            int col = nt * 16 + lr;
            int w0 = (wbase + mt * 16 + lk * 4) >> 1;
            unsigned u0 = (unsigned)f2bf(acc[mt][nt][0]) | ((unsigned)f2bf(acc[mt][nt][1]) << 16);
            unsigned u1 = (unsigned)f2bf(acc[mt][nt][2]) | ((unsigned)f2bf(acc[mt][nt][3]) << 16);
            y2t[col * 64 + (w0 ^ (col & 31))] = u0;
            y2t[col * 64 + ((w0 + 1) ^ (col & 31))] = u1;
        }

    // per-wave segmented max over own 32 rows (channel = lane)
    {
        int c = lane;
        int cur_v = -2; float cur_m = 0.f;
        int hvv = -2; float hkk = 0.f; bool fd = false;
        for (int q = 0; q < 16; ++q) {
            unsigned u = y2t[c * 64 + (((wbase >> 1) + q) ^ (c & 31))];
            #pragma unroll
            for (int e = 0; e < 2; ++e) {
                float d = bf2f((unsigned short)(e ? (u >> 16) : (u & 0xFFFF)));
                int v = __shfl(vid_l, 2 * q + e);
                if (q == 0 && e == 0) { cur_v = v; cur_m = d; }
                else if (v == cur_v) cur_m = fmaxf(cur_m, d);
                else {
                    if (!fd) { hvv = cur_v; hkk = cur_m; fd = true; }
                    else if ((unsigned)cur_v < (unsigned)NVOX)
                        okeys[(size_t)cur_v * 64 + c] = fkey(cur_m);
                    cur_v = v; cur_m = d;
                }
            }
        }
        hv[wave][c] = fd ? hvv : cur_v; hk[wave][c] = fd ? hkk : cur_m;
        tv[wave][c] = cur_v; tk[wave][c] = cur_m; sgl[wave][c] = fd ? 0 : 1;
    }
    __syncthreads();
    if (t < 64) {
        int cv = hv[0][t]; float cm = hk[0][t]; bool fs = true;
        #pragma unroll
        for (int k2 = 0; k2 < 4; ++k2) {
            if (k2 > 0) {
                int nv = hv[k2][t]; float nm = hk[k2][t];
                if (nv == cv) cm = fmaxf(cm, nm);
                else { flush64(cv, cm, fs, t, okeys); cv = nv; cm = nm; fs = false; }
            }
            if (!sgl[k2][t]) {
                flush64(cv, cm, fs, t, okeys);
                cv = tv[k2][t]; cm = tk[k2][t]; fs = false;
            }
        }
        flush64(cv, cm, true, t, okeys);
    }
    if (t < 128) {
        float s = wsums[0][t] + wsums[1][t] + wsums[2][t] + wsums[3][t];
        atomicAdd(&spart2[(blockIdx.x & 255) * 128 + t], s);
    }
}

__global__ void k_fin2(const float* __restrict__ spart2, float* __restrict__ stats,
                       const float* __restrict__ g2, const float* __restrict__ b2) {
    __shared__ float cs[128];
    int t = threadIdx.x;
    float s = 0.f;
    for (int r = 0; r < 256; ++r) s += spart2[r * 128 + t];
    cs[t] = s;
    __syncthreads();
    if (t < 64) {
        float invn = 1.0f / (float)NPTS;
        float mu = cs[t] * invn;
        float var = cs[64 + t] * invn - mu * mu;
        float sc = rsqrtf(var + BN_EPS) * g2[t];
        stats[256 + t] = sc;
        stats[320 + t] = b2[t] - mu * sc;
    }
}

__global__ void k_out(unsigned* __restrict__ okeys, const float* __restrict__ stats) {
    int i4 = blockIdx.x * 256 + threadIdx.x;  // < NVOX*16
    uint4 u = ((const uint4*)okeys)[i4];
    int c0 = (i4 & 15) * 4;
    float4 o;
    o.x = fmaxf(0.f, fmaf(funkey(u.x), stats[256 + c0 + 0], stats[320 + c0 + 0]));
    o.y = fmaxf(0.f, fmaf(funkey(u.y), stats[256 + c0 + 1], stats[320 + c0 + 1]));
    o.z = fmaxf(0.f, fmaf(funkey(u.z), stats[256 + c0 + 2], stats[320 + c0 + 2]));
    o.w = fmaxf(0.f, fmaf(funkey(u.w), stats[256 + c0 + 3], stats[320 + c0 + 3]));
    ((float4*)okeys)[i4] = o;
}

extern "C" void kernel_launch(void* const* d_in, const int* in_sizes, int n_in,
                              void* d_out, int out_size, void* d_ws, size_t ws_size,
                              hipStream_t stream) {
    const float* xyz = (const float*)d_in[0];
    const float* pf  = (const float*)d_in[1];
    const float* w1  = (const float*)d_in[2];
    const float* g1  = (const float*)d_in[3];
    const float* b1  = (const float*)d_in[4];
    const float* w2  = (const float*)d_in[5];
    const float* g2  = (const float*)d_in[6];
    const float* b2  = (const float*)d_in[7];
    const int*   unq = (const int*)d_in[8];

    float4* spts     = (float4*)d_ws;                        // PAD float4 (24 MB)
    float4* vmeanv   = spts + PAD;                           // NVOX float4 (4 MB)
    int* svid        = (int*)(vmeanv + NVOX);                // PAD ints (6 MB)
    unsigned* xmraw  = (unsigned*)(svid + PAD);              // NVOX*32 f32-fkeys (32 MB)
    int* cntv        = (int*)(xmraw + (size_t)NVOX * 32);    // NVOX
    int* startv      = cntv + NVOX;                          // NVOX
    int* offv        = startv + NVOX;                        // NVOX
    int* bsum        = offv + NVOX;                          // 256
    float* stats     = (float*)(bsum + 256);                 // 1024
    float* spart1    = stats + 1024;                         // 256*64
    float* spart2    = spart1 + 256 * 64;                    // 256*128
    uint4* wfrag     = (uint4*)(spart2 + 256 * 128);         // 8*64 uint4

    unsigned* okeys = (unsigned*)d_out;

    k_init<<<2048, 256, 0, stream>>>(okeys, xmraw, cntv, stats, svid, w2, wfrag);
    k_hist<<<NB_PT, 256, 0, stream>>>(unq, cntv);
    k_scanA<<<256, 256, 0, stream>>>(cntv, startv, bsum);
    k_scanB<<<1, 256, 0, stream>>>(bsum);
    k_scanC<<<256, 256, 0, stream>>>(startv, offv, bsum);
    k_scatter2<<<NB_PT, 256, 0, stream>>>(xyz, pf, unq, offv, spts, svid);
    k_vmean2<<<NVOX / 256, 256, 0, stream>>>(spts, cntv, startv, vmeanv);
    k_passA<<<NB_PT, 256, 0, stream>>>(spts, svid, vmeanv, w1, xmraw, spart1);
    k_fin1<<<1, 64, 0, stream>>>(spart1, stats, g1, b1);
    k_l2<<<NB_L2, 256, 0, stream>>>(spts, svid, vmeanv, w1, xmraw, wfrag, stats,
                                    spart2, okeys);
    k_fin2<<<1, 128, 0, stream>>>(spart2, stats, g2, b2);
    k_out<<<NVOX * 16 / 256, 256, 0, stream>>>(okeys, stats);
}

// Round 7
// 430.362 us; speedup vs baseline: 1.8236x; 1.0705x over previous
//
#include <hip/hip_runtime.h>

#define NPTS 1500000
#define NVOX 262144
#define BN_EPS 1e-3f
#define PAD 1500160        // NB_L2*128
#define NB_PT 5860
#define NB_L2 11720

typedef __attribute__((ext_vector_type(8))) short bf16x8;
typedef __attribute__((ext_vector_type(4))) float f32x4;

__device__ __forceinline__ unsigned fkey(float f) {
    unsigned u = __float_as_uint(f);
    return u ^ ((unsigned)(((int)u) >> 31) | 0x80000000u);
}
__device__ __forceinline__ float funkey(unsigned k) {
    unsigned u = (k & 0x80000000u) ? (k ^ 0x80000000u) : ~k;
    return __uint_as_float(u);
}
#define KEY_NEG_INF 0x007FFFFFu

__device__ __forceinline__ float bf2f(unsigned short h) {
    union { unsigned u; float f; } x; x.u = ((unsigned)h) << 16; return x.f;
}
__device__ __forceinline__ unsigned short f2bf(float f) {
    union { float f; unsigned u; } x; x.f = f;
    unsigned r = x.u + 0x7FFFu + ((x.u >> 16) & 1u);
    return (unsigned short)(r >> 16);
}
__device__ __forceinline__ unsigned packbf(float a, float b) {
    return (unsigned)f2bf(a) | ((unsigned)f2bf(b) << 16);
}

__device__ __forceinline__ void make_feat(float x, float y, float z, float w,
                                          float mx, float my, float mz, float* f) {
    const float VS = 0.32f;
    const float PMX = -74.88f, PMY = -74.88f, PMZ = -2.0f;
    f[0] = x; f[1] = y; f[2] = z; f[3] = w;
    f[4] = x - mx; f[5] = y - my; f[6] = z - mz;
    float cx = floorf((x - PMX) / VS);
    float cy = floorf((y - PMY) / VS);
    float cz = floorf((z - PMZ) / VS);
    f[7] = x - (cx * VS + 0.5f * VS + PMX);
    f[8] = y - (cy * VS + 0.5f * VS + PMY);
    f[9] = z - (cz * VS + 0.5f * VS + PMZ);
    f[10] = sqrtf(x * x + y * y + z * z);
}

// all fills/zeros + w2 frag prepack + svid pad
__global__ void k_init(unsigned* __restrict__ okeys, unsigned* __restrict__ xmraw,
                       int* __restrict__ cntv, float* __restrict__ zf,
                       int* __restrict__ svid, const float* __restrict__ w2,
                       uint4* __restrict__ wfrag) {
    long t0 = (long)blockIdx.x * 256 + threadIdx.x;
    long st = (long)gridDim.x * 256;
    uint4 kneg = make_uint4(KEY_NEG_INF, KEY_NEG_INF, KEY_NEG_INF, KEY_NEG_INF);
    for (long i = t0; i < (long)NVOX * 16; i += st) ((uint4*)okeys)[i] = kneg;
    for (long i = t0; i < (long)NVOX * 8; i += st) ((uint4*)xmraw)[i] = kneg;
    for (long i = t0; i < NVOX / 4; i += st) ((int4*)cntv)[i] = make_int4(0, 0, 0, 0);
    for (long i = t0; i < (1024 + 256 * 64 + 256 * 128) / 4; i += st)
        ((float4*)zf)[i] = make_float4(0.f, 0.f, 0.f, 0.f);
    if (t0 < PAD - NPTS) svid[NPTS + t0] = -1;
    if (blockIdx.x == 0 && threadIdx.x < 64) {
        int l = threadIdx.x;
        int lr = l & 15, lk = l >> 4;
        #pragma unroll
        for (int nt = 0; nt < 4; ++nt)
            #pragma unroll
            for (int kt = 0; kt < 2; ++kt) {
                int col = nt * 16 + lr;
                int kb = kt * 32 + lk * 8;
                unsigned u[4];
                #pragma unroll
                for (int j = 0; j < 4; ++j) {
                    float a = w2[(kb + 2 * j) * 64 + col];
                    float b = w2[(kb + 2 * j + 1) * 64 + col];
                    u[j] = packbf(a, b);
                }
                wfrag[(nt * 2 + kt) * 64 + l] = make_uint4(u[0], u[1], u[2], u[3]);
            }
    }
}

__global__ void k_hist(const int* __restrict__ unq, int* __restrict__ cntv) {
    int i = blockIdx.x * blockDim.x + threadIdx.x;
    if (i < NPTS) atomicAdd(&cntv[unq[i]], 1);
}

__global__ void k_scanA(const int* __restrict__ cntv, int* __restrict__ startv,
                        int* __restrict__ bsum) {
    __shared__ int lds[256];
    int t = threadIdx.x;
    int idx4 = blockIdx.x * 256 + t;
    int4 cv = ((const int4*)cntv)[idx4];
    int s0 = cv.x, s1 = s0 + cv.y, s2 = s1 + cv.z, T = s2 + cv.w;
    lds[t] = T;
    __syncthreads();
    for (int o = 1; o < 256; o <<= 1) {
        int v = (t >= o) ? lds[t - o] : 0;
        __syncthreads();
        lds[t] += v;
        __syncthreads();
    }
    int excl = lds[t] - T;
    int4 ov; ov.x = excl; ov.y = excl + s0; ov.z = excl + s1; ov.w = excl + s2;
    ((int4*)startv)[idx4] = ov;
    if (t == 255) bsum[blockIdx.x] = lds[255];
}

__global__ void k_scanB(int* __restrict__ bsum) {
    __shared__ int lds[256];
    int t = threadIdx.x;
    int b = bsum[t];
    lds[t] = b;
    __syncthreads();
    for (int o = 1; o < 256; o <<= 1) {
        int v = (t >= o) ? lds[t - o] : 0;
        __syncthreads();
        lds[t] += v;
        __syncthreads();
    }
    bsum[t] = lds[t] - b;
}

__global__ void k_scanC(int* __restrict__ startv, int* __restrict__ offv,
                        const int* __restrict__ bsum) {
    int t = threadIdx.x;
    int idx4 = blockIdx.x * 256 + t;
    int add = bsum[blockIdx.x];
    int4 v = ((int4*)startv)[idx4];
    v.x += add; v.y += add; v.z += add; v.w += add;
    ((int4*)startv)[idx4] = v;
    ((int4*)offv)[idx4] = v;
}

__global__ void k_scatter2(const float* __restrict__ xyz, const float* __restrict__ pf,
                           const int* __restrict__ unq, int* __restrict__ offv,
                           float4* __restrict__ spts, int* __restrict__ svid) {
    int i = blockIdx.x * blockDim.x + threadIdx.x;
    if (i >= NPTS) return;
    int v = unq[i];
    int pos = atomicAdd(&offv[v], 1);
    float4 p;
    p.x = xyz[3 * i + 0]; p.y = xyz[3 * i + 1]; p.z = xyz[3 * i + 2]; p.w = pf[i];
    spts[pos] = p;
    svid[pos] = v;
}

__global__ void k_vmean2(const float4* __restrict__ spts, const int* __restrict__ cntv,
                         const int* __restrict__ startv, float4* __restrict__ vmeanv) {
    int v = blockIdx.x * 256 + threadIdx.x;
    int cnt = cntv[v];
    if (!cnt) return;
    int st = startv[v];
    float sx = 0, sy = 0, sz = 0;
    for (int j = 0; j < cnt; ++j) {
        float4 p = spts[st + j];
        sx += p.x; sy += p.y; sz += p.z;
    }
    float inv = 1.0f / (float)cnt;
    vmeanv[v] = make_float4(sx * inv, sy * inv, sz * inv, 0.f);
}

__device__ __forceinline__ void flush32(int v, float m, bool atom, int c,
                                        unsigned* __restrict__ xm) {
    if ((unsigned)v >= (unsigned)NVOX) return;
    if (atom) atomicMax(&xm[(size_t)v * 32 + c], fkey(m));
    else xm[(size_t)v * 32 + c] = fkey(m);
}
__device__ __forceinline__ void flush64(int v, float m, bool atom, int c,
                                        unsigned* __restrict__ ok) {
    if ((unsigned)v >= (unsigned)NVOX) return;
    if (atom) atomicMax(&ok[(size_t)v * 64 + c], fkey(m));
    else ok[(size_t)v * 64 + c] = fkey(m);
}

// passA (barrier-free, per-wave): 32 rows/wave; 2 lanes/row x 16 ch each ->
// per-wave LDS tile -> half-wave segmented scan -> BN1 partials + raw-y1 max
__global__ __launch_bounds__(256) void k_passA(
    const float4* __restrict__ spts, const int* __restrict__ svid,
    const float4* __restrict__ vmeanv, const float* __restrict__ w1,
    unsigned* __restrict__ xmraw, float* __restrict__ spart1) {
    __shared__ float ylds[4][32 * 33];
    int t = threadIdx.x;
    int lane = t & 63, wave = t >> 6;
    int rl = lane & 31, half = lane >> 5;
    long grow = (long)blockIdx.x * 128 + wave * 32 + rl;
    int vid = svid[grow];
    float yv[16];
    #pragma unroll
    for (int j = 0; j < 16; ++j) yv[j] = 0.f;
    if (vid >= 0) {
        float4 p = spts[grow];
        float4 vm = vmeanv[vid];
        float f[11];
        make_feat(p.x, p.y, p.z, p.w, vm.x, vm.y, vm.z, f);
        const float4* w1f = (const float4*)w1;
        #pragma unroll
        for (int k = 0; k < 11; ++k) {
            float fk = f[k];
            #pragma unroll
            for (int q = 0; q < 4; ++q) {
                float4 wq = w1f[k * 8 + half * 4 + q];
                yv[4 * q + 0] = fmaf(fk, wq.x, yv[4 * q + 0]);
                yv[4 * q + 1] = fmaf(fk, wq.y, yv[4 * q + 1]);
                yv[4 * q + 2] = fmaf(fk, wq.z, yv[4 * q + 2]);
                yv[4 * q + 3] = fmaf(fk, wq.w, yv[4 * q + 3]);
            }
        }
    }
    float* yw = &ylds[wave][0];
    #pragma unroll
    for (int j = 0; j < 16; ++j) yw[rl * 33 + half * 16 + j] = yv[j];
    asm volatile("s_waitcnt lgkmcnt(0)" ::: "memory");
    __builtin_amdgcn_sched_barrier(0);
    // scan channel c = rl over rows [half*16, half*16+16)
    int c = rl;
    float sa = 0.f, sq = 0.f;
    int cur_v = -2; float cur_m = 0.f; bool first = true;
    #pragma unroll
    for (int i = 0; i < 16; ++i) {
        int r = half * 16 + i;
        float y = yw[r * 33 + c];
        int v = __shfl(vid, r);
        sa += y; sq += y * y;
        if (i == 0) { cur_v = v; cur_m = y; }
        else if (v == cur_v) cur_m = fmaxf(cur_m, y);
        else {
            flush32(cur_v, cur_m, first, c, xmraw);
            first = false; cur_v = v; cur_m = y;
        }
    }
    flush32(cur_v, cur_m, true, c, xmraw);
    sa += __shfl_xor(sa, 32);
    sq += __shfl_xor(sq, 32);
    if (half == 0) {
        int slot = (blockIdx.x * 4 + wave) & 255;
        atomicAdd(&spart1[slot * 64 + c], sa);
        atomicAdd(&spart1[slot * 64 + 32 + c], sq);
    }
}

__global__ void k_fin1(const float* __restrict__ spart1, float* __restrict__ stats,
                       const float* __restrict__ g1, const float* __restrict__ b1) {
    __shared__ float cs[64];
    int t = threadIdx.x;
    float s = 0.f;
    for (int r = 0; r < 256; ++r) s += spart1[r * 64 + t];
    cs[t] = s;
    __syncthreads();
    if (t < 32) {
        float invn = 1.0f / (float)NPTS;
        float mu = cs[t] * invn;
        float var = cs[32 + t] * invn - mu * mu;
        float sc = rsqrtf(var + BN_EPS) * g1[t];
        stats[64 + t] = sc;
        stats[96 + t] = b1[t] - mu * sc;
    }
}

// k_l2 (barrier-free, per-wave): 32 rows/wave. 2 lanes/row build 16ch of
// [z1|z(xm)] each -> per-wave swizzled Abuf -> MFMA -> per-wave y2t [64][17]
// -> per-wave segmented max (head/tail atomics) + BN2 partials.
__global__ __launch_bounds__(256) void k_l2(
    const float4* __restrict__ spts, const int* __restrict__ svid,
    const float4* __restrict__ vmeanv, const float* __restrict__ w1,
    const unsigned* __restrict__ xmraw, const uint4* __restrict__ wfrag,
    const float* __restrict__ stats, float* __restrict__ spart2,
    unsigned* __restrict__ okeys) {
    __shared__ unsigned Abuf[4][32 * 32];
    __shared__ unsigned y2t[4][64 * 17];
    int t = threadIdx.x;
    int lane = t & 63, wave = t >> 6;
    int rl = lane & 31, half = lane >> 5;
    int lr = lane & 15, lk = lane >> 4;
    long brow = (long)blockIdx.x * 128 + wave * 32;
    int vid = svid[brow + rl];

    unsigned zpk[8], xpk[8];
    if (vid >= 0) {
        float4 p = spts[brow + rl];
        float4 vm = vmeanv[vid];
        float f[11];
        make_feat(p.x, p.y, p.z, p.w, vm.x, vm.y, vm.z, f);
        float yv[16];
        #pragma unroll
        for (int j = 0; j < 16; ++j) yv[j] = 0.f;
        const float4* w1f = (const float4*)w1;
        #pragma unroll
        for (int k = 0; k < 11; ++k) {
            float fk = f[k];
            #pragma unroll
            for (int q = 0; q < 4; ++q) {
                float4 wq = w1f[k * 8 + half * 4 + q];
                yv[4 * q + 0] = fmaf(fk, wq.x, yv[4 * q + 0]);
                yv[4 * q + 1] = fmaf(fk, wq.y, yv[4 * q + 1]);
                yv[4 * q + 2] = fmaf(fk, wq.z, yv[4 * q + 2]);
                yv[4 * q + 3] = fmaf(fk, wq.w, yv[4 * q + 3]);
            }
        }
        const uint4* xr = (const uint4*)(xmraw + (size_t)vid * 32);
        uint4 xq[4];
        #pragma unroll
        for (int q = 0; q < 4; ++q) xq[q] = xr[half * 4 + q];
        const unsigned* xu = (const unsigned*)xq;
        #pragma unroll
        for (int q = 0; q < 4; ++q) {
            float4 sc = ((const float4*)(stats + 64))[half * 4 + q];
            float4 sh = ((const float4*)(stats + 96))[half * 4 + q];
            float z0 = fmaxf(0.f, fmaf(yv[4 * q + 0], sc.x, sh.x));
            float z1 = fmaxf(0.f, fmaf(yv[4 * q + 1], sc.y, sh.y));
            float z2 = fmaxf(0.f, fmaf(yv[4 * q + 2], sc.z, sh.z));
            float z3 = fmaxf(0.f, fmaf(yv[4 * q + 3], sc.w, sh.w));
            zpk[2 * q + 0] = packbf(z0, z1);
            zpk[2 * q + 1] = packbf(z2, z3);
            float x0 = fmaxf(0.f, fmaf(funkey(xu[4 * q + 0]), sc.x, sh.x));
            float x1 = fmaxf(0.f, fmaf(funkey(xu[4 * q + 1]), sc.y, sh.y));
            float x2 = fmaxf(0.f, fmaf(funkey(xu[4 * q + 2]), sc.z, sh.z));
            float x3 = fmaxf(0.f, fmaf(funkey(xu[4 * q + 3]), sc.w, sh.w));
            xpk[2 * q + 0] = packbf(x0, x1);
            xpk[2 * q + 1] = packbf(x2, x3);
        }
    } else {
        #pragma unroll
        for (int q = 0; q < 8; ++q) { zpk[q] = 0u; xpk[q] = 0u; }
    }
    {
        uint4* arow = (uint4*)&Abuf[wave][rl * 32];
        int sw = rl & 7;
        arow[(2 * half + 0) ^ sw] = *(const uint4*)&zpk[0];
        arow[(2 * half + 1) ^ sw] = *(const uint4*)&zpk[4];
        arow[(4 + 2 * half) ^ sw] = *(const uint4*)&xpk[0];
        arow[(5 + 2 * half) ^ sw] = *(const uint4*)&xpk[4];
    }
    asm volatile("s_waitcnt lgkmcnt(0)" ::: "memory");
    __builtin_amdgcn_sched_barrier(0);

    uint4 bw[8];
    #pragma unroll
    for (int q = 0; q < 8; ++q) bw[q] = wfrag[q * 64 + lane];

    bf16x8 afr[2][2];
    #pragma unroll
    for (int mt = 0; mt < 2; ++mt)
        #pragma unroll
        for (int kt = 0; kt < 2; ++kt) {
            int riw = mt * 16 + lr;
            uint4 uu = ((const uint4*)&Abuf[wave][riw * 32])[(kt * 4 + lk) ^ (riw & 7)];
            afr[mt][kt] = __builtin_bit_cast(bf16x8, uu);
        }
    f32x4 acc[2][4];
    #pragma unroll
    for (int mt = 0; mt < 2; ++mt)
        #pragma unroll
        for (int nt = 0; nt < 4; ++nt) {
            acc[mt][nt] = (f32x4){0.f, 0.f, 0.f, 0.f};
            #pragma unroll
            for (int kt = 0; kt < 2; ++kt)
                acc[mt][nt] = __builtin_amdgcn_mfma_f32_16x16x32_bf16(
                    afr[mt][kt], __builtin_bit_cast(bf16x8, bw[nt * 2 + kt]),
                    acc[mt][nt], 0, 0, 0);
        }

    // y2t store: [col][17] uints, word w holds rows 2w,2w+1 of this wave
    #pragma unroll
    for (int mt = 0; mt < 2; ++mt)
        #pragma unroll
        for (int nt = 0; nt < 4; ++nt) {
            int col = nt * 16 + lr;
            int w0 = mt * 8 + lk * 2;
            y2t[wave][col * 17 + w0] = packbf(acc[mt][nt][0], acc[mt][nt][1]);
            y2t[wave][col * 17 + w0 + 1] = packbf(acc[mt][nt][2], acc[mt][nt][3]);
        }

    // BN2 partials (exact f32)
    {
        float sa[4] = {0.f, 0.f, 0.f, 0.f}, sq[4] = {0.f, 0.f, 0.f, 0.f};
        #pragma unroll
        for (int mt = 0; mt < 2; ++mt)
            #pragma unroll
            for (int nt = 0; nt < 4; ++nt)
                #pragma unroll
                for (int e = 0; e < 4; ++e) {
                    float v = acc[mt][nt][e];
                    sa[nt] += v; sq[nt] += v * v;
                }
        #pragma unroll
        for (int nt = 0; nt < 4; ++nt) {
            sa[nt] += __shfl_xor(sa[nt], 16); sa[nt] += __shfl_xor(sa[nt], 32);
            sq[nt] += __shfl_xor(sq[nt], 16); sq[nt] += __shfl_xor(sq[nt], 32);
        }
        if (lk == 0) {
            int slot = (blockIdx.x * 4 + wave) & 255;
            #pragma unroll
            for (int nt = 0; nt < 4; ++nt) {
                atomicAdd(&spart2[slot * 128 + nt * 16 + lr], sa[nt]);
                atomicAdd(&spart2[slot * 128 + 64 + nt * 16 + lr], sq[nt]);
            }
        }
    }
    asm volatile("s_waitcnt lgkmcnt(0)" ::: "memory");
    __builtin_amdgcn_sched_barrier(0);

    // per-wave segmented max over own 32 rows; channel = lane
    {
        int c = lane;
        int cur_v = -2; float cur_m = 0.f; bool first = true;
        #pragma unroll
        for (int q = 0; q < 16; ++q) {
            unsigned u = y2t[wave][c * 17 + q];
            #pragma unroll
            for (int e = 0; e < 2; ++e) {
                float d = bf2f((unsigned short)(e ? (u >> 16) : (u & 0xFFFF)));
                int v = __shfl(vid, 2 * q + e);
                if (q == 0 && e == 0) { cur_v = v; cur_m = d; }
                else if (v == cur_v) cur_m = fmaxf(cur_m, d);
                else {
                    flush64(cur_v, cur_m, first, c, okeys);
                    first = false; cur_v = v; cur_m = d;
                }
            }
        }
        flush64(cur_v, cur_m, true, c, okeys);
    }
}

__global__ void k_fin2(const float* __restrict__ spart2, float* __restrict__ stats,
                       const float* __restrict__ g2, const float* __restrict__ b2) {
    __shared__ float cs[128];
    int t = threadIdx.x;
    float s = 0.f;
    for (int r = 0; r < 256; ++r) s += spart2[r * 128 + t];
    cs[t] = s;
    __syncthreads();
    if (t < 64) {
        float invn = 1.0f / (float)NPTS;
        float mu = cs[t] * invn;
        float var = cs[64 + t] * invn - mu * mu;
        float sc = rsqrtf(var + BN_EPS) * g2[t];
        stats[256 + t] = sc;
        stats[320 + t] = b2[t] - mu * sc;
    }
}

__global__ void k_out(unsigned* __restrict__ okeys, const float* __restrict__ stats) {
    int i4 = blockIdx.x * 256 + threadIdx.x;  // < NVOX*16
    uint4 u = ((const uint4*)okeys)[i4];
    int c0 = (i4 & 15) * 4;
    float4 o;
    o.x = fmaxf(0.f, fmaf(funkey(u.x), stats[256 + c0 + 0], stats[320 + c0 + 0]));
    o.y = fmaxf(0.f, fmaf(funkey(u.y), stats[256 + c0 + 1], stats[320 + c0 + 1]));
    o.z = fmaxf(0.f, fmaf(funkey(u.z), stats[256 + c0 + 2], stats[320 + c0 + 2]));
    o.w = fmaxf(0.f, fmaf(funkey(u.w), stats[256 + c0 + 3], stats[320 + c0 + 3]));
    ((float4*)okeys)[i4] = o;
}

extern "C" void kernel_launch(void* const* d_in, const int* in_sizes, int n_in,
                              void* d_out, int out_size, void* d_ws, size_t ws_size,
                              hipStream_t stream) {
    const float* xyz = (const float*)d_in[0];
    const float* pf  = (const float*)d_in[1];
    const float* w1  = (const float*)d_in[2];
    const float* g1  = (const float*)d_in[3];
    const float* b1  = (const float*)d_in[4];
    const float* w2  = (const float*)d_in[5];
    const float* g2  = (const float*)d_in[6];
    const float* b2  = (const float*)d_in[7];
    const int*   unq = (const int*)d_in[8];

    float4* spts     = (float4*)d_ws;                        // PAD float4 (24 MB)
    float4* vmeanv   = spts + PAD;                           // NVOX float4 (4 MB)
    int* svid        = (int*)(vmeanv + NVOX);                // PAD ints (6 MB)
    unsigned* xmraw  = (unsigned*)(svid + PAD);              // NVOX*32 f32-fkeys (32 MB)
    int* cntv        = (int*)(xmraw + (size_t)NVOX * 32);    // NVOX
    int* startv      = cntv + NVOX;                          // NVOX
    int* offv        = startv + NVOX;                        // NVOX
    int* bsum        = offv + NVOX;                          // 256
    float* stats     = (float*)(bsum + 256);                 // 1024
    float* spart1    = stats + 1024;                         // 256*64
    float* spart2    = spart1 + 256 * 64;                    // 256*128
    uint4* wfrag     = (uint4*)(spart2 + 256 * 128);         // 8*64 uint4

    unsigned* okeys = (unsigned*)d_out;

    k_init<<<2048, 256, 0, stream>>>(okeys, xmraw, cntv, stats, svid, w2, wfrag);
    k_hist<<<NB_PT, 256, 0, stream>>>(unq, cntv);
    k_scanA<<<256, 256, 0, stream>>>(cntv, startv, bsum);
    k_scanB<<<1, 256, 0, stream>>>(bsum);
    k_scanC<<<256, 256, 0, stream>>>(startv, offv, bsum);
    k_scatter2<<<NB_PT, 256, 0, stream>>>(xyz, pf, unq, offv, spts, svid);
    k_vmean2<<<NVOX / 256, 256, 0, stream>>>(spts, cntv, startv, vmeanv);
    k_passA<<<NB_L2, 256, 0, stream>>>(spts, svid, vmeanv, w1, xmraw, spart1);
    k_fin1<<<1, 64, 0, stream>>>(spart1, stats, g1, b1);
    k_l2<<<NB_L2, 256, 0, stream>>>(spts, svid, vmeanv, w1, xmraw, wfrag, stats,
                                    spart2, okeys);
    k_fin2<<<1, 128, 0, stream>>>(spart2, stats, g2, b2);
    k_out<<<NVOX * 16 / 256, 256, 0, stream>>>(okeys, stats);
}

// Round 8
// 391.699 us; speedup vs baseline: 2.0036x; 1.0987x over previous
//
#include <hip/hip_runtime.h>

#define NPTS 1500000
#define NVOX 262144
#define BN_EPS 1e-3f
#define PAD 1500160        // NB_L2*128
#define NB_PT 5860
#define NB_L2 11720

typedef __attribute__((ext_vector_type(8))) short bf16x8;
typedef __attribute__((ext_vector_type(4))) float f32x4;

__device__ __forceinline__ unsigned fkey(float f) {
    unsigned u = __float_as_uint(f);
    return u ^ ((unsigned)(((int)u) >> 31) | 0x80000000u);
}
__device__ __forceinline__ float funkey(unsigned k) {
    unsigned u = (k & 0x80000000u) ? (k ^ 0x80000000u) : ~k;
    return __uint_as_float(u);
}
#define KEY_NEG_INF 0x007FFFFFu

__device__ __forceinline__ float bf2f(unsigned short h) {
    union { unsigned u; float f; } x; x.u = ((unsigned)h) << 16; return x.f;
}
__device__ __forceinline__ unsigned short f2bf(float f) {
    union { float f; unsigned u; } x; x.f = f;
    unsigned r = x.u + 0x7FFFu + ((x.u >> 16) & 1u);
    return (unsigned short)(r >> 16);
}
__device__ __forceinline__ unsigned packbf(float a, float b) {
    return (unsigned)f2bf(a) | ((unsigned)f2bf(b) << 16);
}

__device__ __forceinline__ void make_feat(float x, float y, float z, float w,
                                          float mx, float my, float mz, float* f) {
    const float VS = 0.32f;
    const float PMX = -74.88f, PMY = -74.88f, PMZ = -2.0f;
    f[0] = x; f[1] = y; f[2] = z; f[3] = w;
    f[4] = x - mx; f[5] = y - my; f[6] = z - mz;
    float cx = floorf((x - PMX) / VS);
    float cy = floorf((y - PMY) / VS);
    float cz = floorf((z - PMZ) / VS);
    f[7] = x - (cx * VS + 0.5f * VS + PMX);
    f[8] = y - (cy * VS + 0.5f * VS + PMY);
    f[9] = z - (cz * VS + 0.5f * VS + PMZ);
    f[10] = sqrtf(x * x + y * y + z * z);
}

// all fills/zeros + w2 frag prepack + svid pad
__global__ void k_init(unsigned* __restrict__ okeys, unsigned* __restrict__ xmraw,
                       int* __restrict__ cntv, float* __restrict__ zf,
                       int* __restrict__ svid, const float* __restrict__ w2,
                       uint4* __restrict__ wfrag) {
    long t0 = (long)blockIdx.x * 256 + threadIdx.x;
    long st = (long)gridDim.x * 256;
    uint4 kneg = make_uint4(KEY_NEG_INF, KEY_NEG_INF, KEY_NEG_INF, KEY_NEG_INF);
    for (long i = t0; i < (long)NVOX * 16; i += st) ((uint4*)okeys)[i] = kneg;
    for (long i = t0; i < (long)NVOX * 8; i += st) ((uint4*)xmraw)[i] = kneg;
    for (long i = t0; i < NVOX / 4; i += st) ((int4*)cntv)[i] = make_int4(0, 0, 0, 0);
    for (long i = t0; i < (1024 + 256 * 64 + 256 * 128) / 4; i += st)
        ((float4*)zf)[i] = make_float4(0.f, 0.f, 0.f, 0.f);
    if (t0 < PAD - NPTS) svid[NPTS + t0] = -1;
    if (blockIdx.x == 0 && threadIdx.x < 64) {
        int l = threadIdx.x;
        int lr = l & 15, lk = l >> 4;
        #pragma unroll
        for (int nt = 0; nt < 4; ++nt)
            #pragma unroll
            for (int kt = 0; kt < 2; ++kt) {
                int col = nt * 16 + lr;
                int kb = kt * 32 + lk * 8;
                unsigned u[4];
                #pragma unroll
                for (int j = 0; j < 4; ++j) {
                    float a = w2[(kb + 2 * j) * 64 + col];
                    float b = w2[(kb + 2 * j + 1) * 64 + col];
                    u[j] = packbf(a, b);
                }
                wfrag[(nt * 2 + kt) * 64 + l] = make_uint4(u[0], u[1], u[2], u[3]);
            }
    }
}

__global__ void k_hist(const int* __restrict__ unq, int* __restrict__ cntv) {
    int i = blockIdx.x * blockDim.x + threadIdx.x;
    if (i < NPTS) atomicAdd(&cntv[unq[i]], 1);
}

__global__ void k_scanA(const int* __restrict__ cntv, int* __restrict__ startv,
                        int* __restrict__ bsum) {
    __shared__ int lds[256];
    int t = threadIdx.x;
    int idx4 = blockIdx.x * 256 + t;
    int4 cv = ((const int4*)cntv)[idx4];
    int s0 = cv.x, s1 = s0 + cv.y, s2 = s1 + cv.z, T = s2 + cv.w;
    lds[t] = T;
    __syncthreads();
    for (int o = 1; o < 256; o <<= 1) {
        int v = (t >= o) ? lds[t - o] : 0;
        __syncthreads();
        lds[t] += v;
        __syncthreads();
    }
    int excl = lds[t] - T;
    int4 ov; ov.x = excl; ov.y = excl + s0; ov.z = excl + s1; ov.w = excl + s2;
    ((int4*)startv)[idx4] = ov;
    if (t == 255) bsum[blockIdx.x] = lds[255];
}

__global__ void k_scanB(int* __restrict__ bsum) {
    __shared__ int lds[256];
    int t = threadIdx.x;
    int b = bsum[t];
    lds[t] = b;
    __syncthreads();
    for (int o = 1; o < 256; o <<= 1) {
        int v = (t >= o) ? lds[t - o] : 0;
        __syncthreads();
        lds[t] += v;
        __syncthreads();
    }
    bsum[t] = lds[t] - b;
}

__global__ void k_scanC(int* __restrict__ startv, int* __restrict__ offv,
                        const int* __restrict__ bsum) {
    int t = threadIdx.x;
    int idx4 = blockIdx.x * 256 + t;
    int add = bsum[blockIdx.x];
    int4 v = ((int4*)startv)[idx4];
    v.x += add; v.y += add; v.z += add; v.w += add;
    ((int4*)startv)[idx4] = v;
    ((int4*)offv)[idx4] = v;
}

__global__ void k_scatter2(const float* __restrict__ xyz, const float* __restrict__ pf,
                           const int* __restrict__ unq, int* __restrict__ offv,
                           float4* __restrict__ spts, int* __restrict__ svid) {
    int i = blockIdx.x * blockDim.x + threadIdx.x;
    if (i >= NPTS) return;
    int v = unq[i];
    int pos = atomicAdd(&offv[v], 1);
    float4 p;
    p.x = xyz[3 * i + 0]; p.y = xyz[3 * i + 1]; p.z = xyz[3 * i + 2]; p.w = pf[i];
    spts[pos] = p;
    svid[pos] = v;
}

__global__ void k_vmean2(const float4* __restrict__ spts, const int* __restrict__ cntv,
                         const int* __restrict__ startv, float4* __restrict__ vmeanv) {
    int v = blockIdx.x * 256 + threadIdx.x;
    int cnt = cntv[v];
    if (!cnt) return;
    int st = startv[v];
    float sx = 0, sy = 0, sz = 0;
    for (int j = 0; j < cnt; ++j) {
        float4 p = spts[st + j];
        sx += p.x; sy += p.y; sz += p.z;
    }
    float inv = 1.0f / (float)cnt;
    vmeanv[v] = make_float4(sx * inv, sy * inv, sz * inv, 0.f);
}

__device__ __forceinline__ void flush32(int v, float m, bool atom, int c,
                                        unsigned* __restrict__ xm) {
    if ((unsigned)v >= (unsigned)NVOX) return;
    if (atom) atomicMax(&xm[(size_t)v * 32 + c], fkey(m));
    else xm[(size_t)v * 32 + c] = fkey(m);
}
__device__ __forceinline__ void flush64(int v, float m, bool atom, int c,
                                        unsigned* __restrict__ ok) {
    if ((unsigned)v >= (unsigned)NVOX) return;
    if (atom) atomicMax(&ok[(size_t)v * 64 + c], fkey(m));
    else ok[(size_t)v * 64 + c] = fkey(m);
}

// passA: per-wave; 2 lanes/row x 16 ch -> y1 f32; store y1 bf16 to global;
// LDS transpose tile -> half-wave segmented scan -> BN1 partials + raw-y1 max
__global__ __launch_bounds__(256) void k_passA(
    const float4* __restrict__ spts, const int* __restrict__ svid,
    const float4* __restrict__ vmeanv, const float* __restrict__ w1,
    unsigned* __restrict__ xmraw, unsigned* __restrict__ y1bf,
    float* __restrict__ spart1) {
    __shared__ float ylds[4][32 * 33];
    int t = threadIdx.x;
    int lane = t & 63, wave = t >> 6;
    int rl = lane & 31, half = lane >> 5;
    long grow = (long)blockIdx.x * 128 + wave * 32 + rl;
    int vid = svid[grow];
    float yv[16];
    #pragma unroll
    for (int j = 0; j < 16; ++j) yv[j] = 0.f;
    if (vid >= 0) {
        float4 p = spts[grow];
        float4 vm = vmeanv[vid];
        float f[11];
        make_feat(p.x, p.y, p.z, p.w, vm.x, vm.y, vm.z, f);
        const float4* w1f = (const float4*)w1;
        #pragma unroll
        for (int k = 0; k < 11; ++k) {
            float fk = f[k];
            #pragma unroll
            for (int q = 0; q < 4; ++q) {
                float4 wq = w1f[k * 8 + half * 4 + q];
                yv[4 * q + 0] = fmaf(fk, wq.x, yv[4 * q + 0]);
                yv[4 * q + 1] = fmaf(fk, wq.y, yv[4 * q + 1]);
                yv[4 * q + 2] = fmaf(fk, wq.z, yv[4 * q + 2]);
                yv[4 * q + 3] = fmaf(fk, wq.w, yv[4 * q + 3]);
            }
        }
    }
    // store y1 as bf16 (raw, pre-BN)
    {
        unsigned ypk[8];
        #pragma unroll
        for (int q = 0; q < 8; ++q) ypk[q] = packbf(yv[2 * q], yv[2 * q + 1]);
        uint4* yb = (uint4*)y1bf;
        yb[grow * 4 + half * 2 + 0] = *(const uint4*)&ypk[0];
        yb[grow * 4 + half * 2 + 1] = *(const uint4*)&ypk[4];
    }
    float* yw = &ylds[wave][0];
    #pragma unroll
    for (int j = 0; j < 16; ++j) yw[rl * 33 + half * 16 + j] = yv[j];
    asm volatile("s_waitcnt lgkmcnt(0)" ::: "memory");
    __builtin_amdgcn_sched_barrier(0);
    int c = rl;
    float sa = 0.f, sq = 0.f;
    int cur_v = -2; float cur_m = 0.f; bool first = true;
    #pragma unroll
    for (int i = 0; i < 16; ++i) {
        int r = half * 16 + i;
        float y = yw[r * 33 + c];
        int v = __shfl(vid, r);
        sa += y; sq += y * y;
        if (i == 0) { cur_v = v; cur_m = y; }
        else if (v == cur_v) cur_m = fmaxf(cur_m, y);
        else {
            flush32(cur_v, cur_m, first, c, xmraw);
            first = false; cur_v = v; cur_m = y;
        }
    }
    flush32(cur_v, cur_m, true, c, xmraw);
    sa += __shfl_xor(sa, 32);
    sq += __shfl_xor(sq, 32);
    if (half == 0) {
        int slot = (blockIdx.x * 4 + wave) & 255;
        atomicAdd(&spart1[slot * 64 + c], sa);
        atomicAdd(&spart1[slot * 64 + 32 + c], sq);
    }
}

__global__ void k_fin1(const float* __restrict__ spart1, float* __restrict__ stats,
                       const float* __restrict__ g1, const float* __restrict__ b1) {
    __shared__ float cs[64];
    int t = threadIdx.x;
    float s = 0.f;
    for (int r = 0; r < 256; ++r) s += spart1[r * 64 + t];
    cs[t] = s;
    __syncthreads();
    if (t < 32) {
        float invn = 1.0f / (float)NPTS;
        float mu = cs[t] * invn;
        float var = cs[32 + t] * invn - mu * mu;
        float sc = rsqrtf(var + BN_EPS) * g1[t];
        stats[64 + t] = sc;
        stats[96 + t] = b1[t] - mu * sc;
    }
}

// k_l2 v4: load y1 bf16 (no recompute) + xm gather -> affine/relu/pack ->
// per-wave Abuf -> MFMA -> y2t (aliased over Abuf) -> per-wave segmented max
// + BN2 partials. Barrier-free.
__global__ __launch_bounds__(256) void k_l2(
    const int* __restrict__ svid, const unsigned* __restrict__ y1bf,
    const unsigned* __restrict__ xmraw, const uint4* __restrict__ wfrag,
    const float* __restrict__ stats, float* __restrict__ spart2,
    unsigned* __restrict__ okeys) {
    __shared__ unsigned shbuf[4][1088];   // Abuf [32][32] then y2t [64][17]
    int t = threadIdx.x;
    int lane = t & 63, wave = t >> 6;
    int rl = lane & 31, half = lane >> 5;
    int lr = lane & 15, lk = lane >> 4;
    long brow = (long)blockIdx.x * 128 + wave * 32;
    int vid = svid[brow + rl];

    // independent loads first (hide latency): w2 fragments + y1 row-half
    uint4 bw[8];
    #pragma unroll
    for (int q = 0; q < 8; ++q) bw[q] = wfrag[q * 64 + lane];
    uint4 yu0 = ((const uint4*)y1bf)[(brow + rl) * 4 + half * 2];
    uint4 yu1 = ((const uint4*)y1bf)[(brow + rl) * 4 + half * 2 + 1];

    unsigned zpk[8], xpk[8];
    if (vid >= 0) {
        const uint4* xr = (const uint4*)(xmraw + (size_t)vid * 32);
        uint4 xq[4];
        #pragma unroll
        for (int q = 0; q < 4; ++q) xq[q] = xr[half * 4 + q];
        const unsigned* xu = (const unsigned*)xq;
        unsigned yw[8] = {yu0.x, yu0.y, yu0.z, yu0.w, yu1.x, yu1.y, yu1.z, yu1.w};
        #pragma unroll
        for (int q = 0; q < 4; ++q) {
            float4 sc = ((const float4*)(stats + 64))[half * 4 + q];
            float4 sh = ((const float4*)(stats + 96))[half * 4 + q];
            float yA = bf2f((unsigned short)(yw[2 * q] & 0xFFFF));
            float yB = bf2f((unsigned short)(yw[2 * q] >> 16));
            float yC = bf2f((unsigned short)(yw[2 * q + 1] & 0xFFFF));
            float yD = bf2f((unsigned short)(yw[2 * q + 1] >> 16));
            zpk[2 * q + 0] = packbf(fmaxf(0.f, fmaf(yA, sc.x, sh.x)),
                                    fmaxf(0.f, fmaf(yB, sc.y, sh.y)));
            zpk[2 * q + 1] = packbf(fmaxf(0.f, fmaf(yC, sc.z, sh.z)),
                                    fmaxf(0.f, fmaf(yD, sc.w, sh.w)));
            float x0 = fmaxf(0.f, fmaf(funkey(xu[4 * q + 0]), sc.x, sh.x));
            float x1 = fmaxf(0.f, fmaf(funkey(xu[4 * q + 1]), sc.y, sh.y));
            float x2 = fmaxf(0.f, fmaf(funkey(xu[4 * q + 2]), sc.z, sh.z));
            float x3 = fmaxf(0.f, fmaf(funkey(xu[4 * q + 3]), sc.w, sh.w));
            xpk[2 * q + 0] = packbf(x0, x1);
            xpk[2 * q + 1] = packbf(x2, x3);
        }
    } else {
        #pragma unroll
        for (int q = 0; q < 8; ++q) { zpk[q] = 0u; xpk[q] = 0u; }
    }
    {
        uint4* arow = (uint4*)&shbuf[wave][rl * 32];
        int sw = rl & 7;
        arow[(2 * half + 0) ^ sw] = *(const uint4*)&zpk[0];
        arow[(2 * half + 1) ^ sw] = *(const uint4*)&zpk[4];
        arow[(4 + 2 * half) ^ sw] = *(const uint4*)&xpk[0];
        arow[(5 + 2 * half) ^ sw] = *(const uint4*)&xpk[4];
    }
    asm volatile("s_waitcnt lgkmcnt(0)" ::: "memory");
    __builtin_amdgcn_sched_barrier(0);

    bf16x8 afr[2][2];
    #pragma unroll
    for (int mt = 0; mt < 2; ++mt)
        #pragma unroll
        for (int kt = 0; kt < 2; ++kt) {
            int riw = mt * 16 + lr;
            uint4 uu = ((const uint4*)&shbuf[wave][riw * 32])[(kt * 4 + lk) ^ (riw & 7)];
            afr[mt][kt] = __builtin_bit_cast(bf16x8, uu);
        }
    // fragment reads must land before we overwrite the buffer with y2t
    asm volatile("s_waitcnt lgkmcnt(0)" ::: "memory");
    __builtin_amdgcn_sched_barrier(0);

    f32x4 acc[2][4];
    #pragma unroll
    for (int mt = 0; mt < 2; ++mt)
        #pragma unroll
        for (int nt = 0; nt < 4; ++nt) {
            acc[mt][nt] = (f32x4){0.f, 0.f, 0.f, 0.f};
            #pragma unroll
            for (int kt = 0; kt < 2; ++kt)
                acc[mt][nt] = __builtin_amdgcn_mfma_f32_16x16x32_bf16(
                    afr[mt][kt], __builtin_bit_cast(bf16x8, bw[nt * 2 + kt]),
                    acc[mt][nt], 0, 0, 0);
        }

    // y2t store (bf16 pairs) into the SAME buffer (Abuf dead now)
    unsigned* y2w = &shbuf[wave][0];
    #pragma unroll
    for (int mt = 0; mt < 2; ++mt)
        #pragma unroll
        for (int nt = 0; nt < 4; ++nt) {
            int col = nt * 16 + lr;
            int w0 = mt * 8 + lk * 2;
            y2w[col * 17 + w0] = packbf(acc[mt][nt][0], acc[mt][nt][1]);
            y2w[col * 17 + w0 + 1] = packbf(acc[mt][nt][2], acc[mt][nt][3]);
        }

    // BN2 partials (exact f32) — overlaps LDS drain
    {
        float sa[4] = {0.f, 0.f, 0.f, 0.f}, sq[4] = {0.f, 0.f, 0.f, 0.f};
        #pragma unroll
        for (int mt = 0; mt < 2; ++mt)
            #pragma unroll
            for (int nt = 0; nt < 4; ++nt)
                #pragma unroll
                for (int e = 0; e < 4; ++e) {
                    float v = acc[mt][nt][e];
                    sa[nt] += v; sq[nt] += v * v;
                }
        #pragma unroll
        for (int nt = 0; nt < 4; ++nt) {
            sa[nt] += __shfl_xor(sa[nt], 16); sa[nt] += __shfl_xor(sa[nt], 32);
            sq[nt] += __shfl_xor(sq[nt], 16); sq[nt] += __shfl_xor(sq[nt], 32);
        }
        if (lk == 0) {
            int slot = (blockIdx.x * 4 + wave) & 255;
            #pragma unroll
            for (int nt = 0; nt < 4; ++nt) {
                atomicAdd(&spart2[slot * 128 + nt * 16 + lr], sa[nt]);
                atomicAdd(&spart2[slot * 128 + 64 + nt * 16 + lr], sq[nt]);
            }
        }
    }
    asm volatile("s_waitcnt lgkmcnt(0)" ::: "memory");
    __builtin_amdgcn_sched_barrier(0);

    // per-wave segmented max over own 32 rows; channel = lane
    {
        int c = lane;
        int cur_v = -2; float cur_m = 0.f; bool first = true;
        #pragma unroll
        for (int q = 0; q < 16; ++q) {
            unsigned u = y2w[c * 17 + q];
            #pragma unroll
            for (int e = 0; e < 2; ++e) {
                float d = bf2f((unsigned short)(e ? (u >> 16) : (u & 0xFFFF)));
                int v = __shfl(vid, 2 * q + e);
                if (q == 0 && e == 0) { cur_v = v; cur_m = d; }
                else if (v == cur_v) cur_m = fmaxf(cur_m, d);
                else {
                    flush64(cur_v, cur_m, first, c, okeys);
                    first = false; cur_v = v; cur_m = d;
                }
            }
        }
        flush64(cur_v, cur_m, true, c, okeys);
    }
}

__global__ void k_fin2(const float* __restrict__ spart2, float* __restrict__ stats,
                       const float* __restrict__ g2, const float* __restrict__ b2) {
    __shared__ float cs[128];
    int t = threadIdx.x;
    float s = 0.f;
    for (int r = 0; r < 256; ++r) s += spart2[r * 128 + t];
    cs[t] = s;
    __syncthreads();
    if (t < 64) {
        float invn = 1.0f / (float)NPTS;
        float mu = cs[t] * invn;
        float var = cs[64 + t] * invn - mu * mu;
        float sc = rsqrtf(var + BN_EPS) * g2[t];
        stats[256 + t] = sc;
        stats[320 + t] = b2[t] - mu * sc;
    }
}

__global__ void k_out(unsigned* __restrict__ okeys, const float* __restrict__ stats) {
    int i4 = blockIdx.x * 256 + threadIdx.x;  // < NVOX*16
    uint4 u = ((const uint4*)okeys)[i4];
    int c0 = (i4 & 15) * 4;
    float4 o;
    o.x = fmaxf(0.f, fmaf(funkey(u.x), stats[256 + c0 + 0], stats[320 + c0 + 0]));
    o.y = fmaxf(0.f, fmaf(funkey(u.y), stats[256 + c0 + 1], stats[320 + c0 + 1]));
    o.z = fmaxf(0.f, fmaf(funkey(u.z), stats[256 + c0 + 2], stats[320 + c0 + 2]));
    o.w = fmaxf(0.f, fmaf(funkey(u.w), stats[256 + c0 + 3], stats[320 + c0 + 3]));
    ((float4*)okeys)[i4] = o;
}

extern "C" void kernel_launch(void* const* d_in, const int* in_sizes, int n_in,
                              void* d_out, int out_size, void* d_ws, size_t ws_size,
                              hipStream_t stream) {
    const float* xyz = (const float*)d_in[0];
    const float* pf  = (const float*)d_in[1];
    const float* w1  = (const float*)d_in[2];
    const float* g1  = (const float*)d_in[3];
    const float* b1  = (const float*)d_in[4];
    const float* w2  = (const float*)d_in[5];
    const float* g2  = (const float*)d_in[6];
    const float* b2  = (const float*)d_in[7];
    const int*   unq = (const int*)d_in[8];

    float4* spts     = (float4*)d_ws;                        // PAD float4 (24 MB)
    float4* vmeanv   = spts + PAD;                           // NVOX float4 (4 MB)
    int* svid        = (int*)(vmeanv + NVOX);                // PAD ints (6 MB)
    unsigned* xmraw  = (unsigned*)(svid + PAD);              // NVOX*32 f32-fkeys (32 MB)
    int* cntv        = (int*)(xmraw + (size_t)NVOX * 32);    // NVOX
    int* startv      = cntv + NVOX;                          // NVOX
    int* offv        = startv + NVOX;                        // NVOX
    int* bsum        = offv + NVOX;                          // 256
    float* stats     = (float*)(bsum + 256);                 // 1024
    float* spart1    = stats + 1024;                         // 256*64
    float* spart2    = spart1 + 256 * 64;                    // 256*128
    uint4* wfrag     = (uint4*)(spart2 + 256 * 128);         // 8*64 uint4
    unsigned* y1bf   = (unsigned*)(wfrag + 512);             // PAD*16 uints (96 MB)

    unsigned* okeys = (unsigned*)d_out;

    k_init<<<2048, 256, 0, stream>>>(okeys, xmraw, cntv, stats, svid, w2, wfrag);
    k_hist<<<NB_PT, 256, 0, stream>>>(unq, cntv);
    k_scanA<<<256, 256, 0, stream>>>(cntv, startv, bsum);
    k_scanB<<<1, 256, 0, stream>>>(bsum);
    k_scanC<<<256, 256, 0, stream>>>(startv, offv, bsum);
    k_scatter2<<<NB_PT, 256, 0, stream>>>(xyz, pf, unq, offv, spts, svid);
    k_vmean2<<<NVOX / 256, 256, 0, stream>>>(spts, cntv, startv, vmeanv);
    k_passA<<<NB_L2, 256, 0, stream>>>(spts, svid, vmeanv, w1, xmraw, y1bf, spart1);
    k_fin1<<<1, 64, 0, stream>>>(spart1, stats, g1, b1);
    k_l2<<<NB_L2, 256, 0, stream>>>(svid, y1bf, xmraw, wfrag, stats, spart2, okeys);
    k_fin2<<<1, 128, 0, stream>>>(spart2, stats, g2, b2);
    k_out<<<NVOX * 16 / 256, 256, 0, stream>>>(okeys, stats);
}

// Round 11
// 378.072 us; speedup vs baseline: 2.0758x; 1.0360x over previous
//
#include <hip/hip_runtime.h>

#define NPTS 1500000
#define NVOX 262144
#define BN_EPS 1e-3f
#define PAD 1500160        // NB_L2*128
#define NB_PT 5860
#define NB_L2 11720

typedef __attribute__((ext_vector_type(8))) short bf16x8;
typedef __attribute__((ext_vector_type(4))) float f32x4;

__device__ __forceinline__ unsigned fkey(float f) {
    unsigned u = __float_as_uint(f);
    return u ^ ((unsigned)(((int)u) >> 31) | 0x80000000u);
}
__device__ __forceinline__ float funkey(unsigned k) {
    unsigned u = (k & 0x80000000u) ? (k ^ 0x80000000u) : ~k;
    return __uint_as_float(u);
}
#define KEY_NEG_INF 0x007FFFFFu

__device__ __forceinline__ float bf2f(unsigned short h) {
    union { unsigned u; float f; } x; x.u = ((unsigned)h) << 16; return x.f;
}
__device__ __forceinline__ unsigned short f2bf(float f) {
    union { float f; unsigned u; } x; x.f = f;
    unsigned r = x.u + 0x7FFFu + ((x.u >> 16) & 1u);
    return (unsigned short)(r >> 16);
}
__device__ __forceinline__ unsigned packbf(float a, float b) {
    return (unsigned)f2bf(a) | ((unsigned)f2bf(b) << 16);
}

__device__ __forceinline__ void make_feat(float x, float y, float z, float w,
                                          float mx, float my, float mz, float* f) {
    const float VS = 0.32f;
    const float PMX = -74.88f, PMY = -74.88f, PMZ = -2.0f;
    f[0] = x; f[1] = y; f[2] = z; f[3] = w;
    f[4] = x - mx; f[5] = y - my; f[6] = z - mz;
    float cx = floorf((x - PMX) / VS);
    float cy = floorf((y - PMY) / VS);
    float cz = floorf((z - PMZ) / VS);
    f[7] = x - (cx * VS + 0.5f * VS + PMX);
    f[8] = y - (cy * VS + 0.5f * VS + PMY);
    f[9] = z - (cz * VS + 0.5f * VS + PMZ);
    f[10] = sqrtf(x * x + y * y + z * z);
}

// all fills/zeros + w2 frag prepack + svid pad
__global__ void k_init(unsigned* __restrict__ okeys, unsigned* __restrict__ xmraw,
                       int* __restrict__ cntv, float* __restrict__ zf,
                       int* __restrict__ svid, const float* __restrict__ w2,
                       uint4* __restrict__ wfrag) {
    long t0 = (long)blockIdx.x * 256 + threadIdx.x;
    long st = (long)gridDim.x * 256;
    uint4 kneg = make_uint4(KEY_NEG_INF, KEY_NEG_INF, KEY_NEG_INF, KEY_NEG_INF);
    for (long i = t0; i < (long)NVOX * 16; i += st) ((uint4*)okeys)[i] = kneg;
    for (long i = t0; i < (long)NVOX * 8; i += st) ((uint4*)xmraw)[i] = kneg;
    for (long i = t0; i < NVOX / 4; i += st) ((int4*)cntv)[i] = make_int4(0, 0, 0, 0);
    for (long i = t0; i < (1024 + 256 * 64 + 256 * 128) / 4; i += st)
        ((float4*)zf)[i] = make_float4(0.f, 0.f, 0.f, 0.f);
    if (t0 < PAD - NPTS) svid[NPTS + t0] = -1;
    if (blockIdx.x == 0 && threadIdx.x < 64) {
        int l = threadIdx.x;
        int lr = l & 15, lk = l >> 4;
        #pragma unroll
        for (int nt = 0; nt < 4; ++nt)
            #pragma unroll
            for (int kt = 0; kt < 2; ++kt) {
                int col = nt * 16 + lr;
                int kb = kt * 32 + lk * 8;
                unsigned u[4];
                #pragma unroll
                for (int j = 0; j < 4; ++j) {
                    float a = w2[(kb + 2 * j) * 64 + col];
                    float b = w2[(kb + 2 * j + 1) * 64 + col];
                    u[j] = packbf(a, b);
                }
                wfrag[(nt * 2 + kt) * 64 + l] = make_uint4(u[0], u[1], u[2], u[3]);
            }
    }
}

__global__ void k_hist(const int* __restrict__ unq, int* __restrict__ cntv) {
    int i = blockIdx.x * blockDim.x + threadIdx.x;
    if (i < NPTS) atomicAdd(&cntv[unq[i]], 1);
}

__global__ void k_scanA(const int* __restrict__ cntv, int* __restrict__ startv,
                        int* __restrict__ bsum) {
    __shared__ int lds[256];
    int t = threadIdx.x;
    int idx4 = blockIdx.x * 256 + t;
    int4 cv = ((const int4*)cntv)[idx4];
    int s0 = cv.x, s1 = s0 + cv.y, s2 = s1 + cv.z, T = s2 + cv.w;
    lds[t] = T;
    __syncthreads();
    for (int o = 1; o < 256; o <<= 1) {
        int v = (t >= o) ? lds[t - o] : 0;
        __syncthreads();
        lds[t] += v;
        __syncthreads();
    }
    int excl = lds[t] - T;
    int4 ov; ov.x = excl; ov.y = excl + s0; ov.z = excl + s1; ov.w = excl + s2;
    ((int4*)startv)[idx4] = ov;
    if (t == 255) bsum[blockIdx.x] = lds[255];
}

// scanC with scanB folded in: every block redundantly scans the 256 bsums
__global__ void k_scanC(int* __restrict__ startv, int* __restrict__ offv,
                        const int* __restrict__ bsum) {
    __shared__ int lds[256];
    int t = threadIdx.x;
    int b = bsum[t];
    lds[t] = b;
    __syncthreads();
    for (int o = 1; o < 256; o <<= 1) {
        int v = (t >= o) ? lds[t - o] : 0;
        __syncthreads();
        lds[t] += v;
        __syncthreads();
    }
    int add = (blockIdx.x > 0) ? lds[blockIdx.x - 1] : 0;
    int idx4 = blockIdx.x * 256 + t;
    int4 v = ((int4*)startv)[idx4];
    v.x += add; v.y += add; v.z += add; v.w += add;
    ((int4*)startv)[idx4] = v;
    ((int4*)offv)[idx4] = v;
}

__global__ void k_scatter2(const float* __restrict__ xyz, const float* __restrict__ pf,
                           const int* __restrict__ unq, int* __restrict__ offv,
                           float4* __restrict__ spts, int* __restrict__ svid) {
    int i = blockIdx.x * blockDim.x + threadIdx.x;
    if (i >= NPTS) return;
    int v = unq[i];
    int pos = atomicAdd(&offv[v], 1);
    float4 p;
    p.x = xyz[3 * i + 0]; p.y = xyz[3 * i + 1]; p.z = xyz[3 * i + 2]; p.w = pf[i];
    spts[pos] = p;
    svid[pos] = v;
}

__global__ void k_vmean2(const float4* __restrict__ spts, const int* __restrict__ cntv,
                         const int* __restrict__ startv, float4* __restrict__ vmeanv) {
    int v = blockIdx.x * 256 + threadIdx.x;
    int cnt = cntv[v];
    if (!cnt) return;
    int st = startv[v];
    float sx = 0, sy = 0, sz = 0;
    for (int j = 0; j < cnt; ++j) {
        float4 p = spts[st + j];
        sx += p.x; sy += p.y; sz += p.z;
    }
    float inv = 1.0f / (float)cnt;
    vmeanv[v] = make_float4(sx * inv, sy * inv, sz * inv, 0.f);
}

__device__ __forceinline__ void flush32(int v, float m, bool atom, int c,
                                        unsigned* __restrict__ xm) {
    if ((unsigned)v >= (unsigned)NVOX) return;
    if (atom) atomicMax(&xm[(size_t)v * 32 + c], fkey(m));
    else xm[(size_t)v * 32 + c] = fkey(m);
}
__device__ __forceinline__ void flush64(int v, float m, bool atom, int c,
                                        unsigned* __restrict__ ok) {
    if ((unsigned)v >= (unsigned)NVOX) return;
    if (atom) atomicMax(&ok[(size_t)v * 64 + c], fkey(m));
    else ok[(size_t)v * 64 + c] = fkey(m);
}

// passA: per-wave; 2 lanes/row x 16 ch -> y1 f32; store y1 bf16 to global;
// LDS transpose tile -> ROUND-8-STYLE segmented scan (unconditional shfl —
// a divergent-branch shfl here read inactive lanes and returned 0 [r9/r10 bug])
__global__ __launch_bounds__(256) void k_passA(
    const float4* __restrict__ spts, const int* __restrict__ svid,
    const float4* __restrict__ vmeanv, const float* __restrict__ w1,
    unsigned* __restrict__ xmraw, unsigned* __restrict__ y1bf,
    float* __restrict__ spart1) {
    __shared__ float ylds[4][32 * 33];
    int t = threadIdx.x;
    int lane = t & 63, wave = t >> 6;
    int rl = lane & 31, half = lane >> 5;
    long grow = (long)blockIdx.x * 128 + wave * 32 + rl;
    int vid = svid[grow];
    float yv[16];
    #pragma unroll
    for (int j = 0; j < 16; ++j) yv[j] = 0.f;
    if (vid >= 0) {
        float4 p = spts[grow];
        float4 vm = vmeanv[vid];
        float f[11];
        make_feat(p.x, p.y, p.z, p.w, vm.x, vm.y, vm.z, f);
        const float4* w1f = (const float4*)w1;
        #pragma unroll
        for (int k = 0; k < 11; ++k) {
            float fk = f[k];
            #pragma unroll
            for (int q = 0; q < 4; ++q) {
                float4 wq = w1f[k * 8 + half * 4 + q];
                yv[4 * q + 0] = fmaf(fk, wq.x, yv[4 * q + 0]);
                yv[4 * q + 1] = fmaf(fk, wq.y, yv[4 * q + 1]);
                yv[4 * q + 2] = fmaf(fk, wq.z, yv[4 * q + 2]);
                yv[4 * q + 3] = fmaf(fk, wq.w, yv[4 * q + 3]);
            }
        }
    }
    // store y1 as bf16 (raw, pre-BN)
    {
        unsigned ypk[8];
        #pragma unroll
        for (int q = 0; q < 8; ++q) ypk[q] = packbf(yv[2 * q], yv[2 * q + 1]);
        uint4* yb = (uint4*)y1bf;
        yb[grow * 4 + half * 2 + 0] = *(const uint4*)&ypk[0];
        yb[grow * 4 + half * 2 + 1] = *(const uint4*)&ypk[4];
    }
    float* yw = &ylds[wave][0];
    #pragma unroll
    for (int j = 0; j < 16; ++j) yw[rl * 33 + half * 16 + j] = yv[j];
    asm volatile("s_waitcnt lgkmcnt(0)" ::: "memory");
    __builtin_amdgcn_sched_barrier(0);
    int c = rl;
    int r0 = half * 16;
    float sa = 0.f, sq = 0.f;
    int cur_v = -2; float cur_m = 0.f; bool first = true;
    #pragma unroll
    for (int i = 0; i < 16; ++i) {
        int r = r0 + i;
        float y = yw[r * 33 + c];
        int v = __shfl(vid, r);   // unconditional: all lanes active
        sa += y; sq += y * y;
        if (i == 0) { cur_v = v; cur_m = y; }
        else if (v == cur_v) cur_m = fmaxf(cur_m, y);
        else {
            flush32(cur_v, cur_m, first, c, xmraw);
            first = false; cur_v = v; cur_m = y;
        }
    }
    flush32(cur_v, cur_m, true, c, xmraw);
    sa += __shfl_xor(sa, 32);
    sq += __shfl_xor(sq, 32);
    if (half == 0) {
        int slot = (blockIdx.x * 4 + wave) & 255;
        atomicAdd(&spart1[slot * 64 + c], sa);
        atomicAdd(&spart1[slot * 64 + 32 + c], sq);
    }
}

__global__ void k_fin1(const float* __restrict__ spart1, float* __restrict__ stats,
                       const float* __restrict__ g1, const float* __restrict__ b1) {
    __shared__ float cs[64];
    int t = threadIdx.x;
    float s = 0.f;
    for (int r = 0; r < 256; ++r) s += spart1[r * 64 + t];
    cs[t] = s;
    __syncthreads();
    if (t < 32) {
        float invn = 1.0f / (float)NPTS;
        float mu = cs[t] * invn;
        float var = cs[32 + t] * invn - mu * mu;
        float sc = rsqrtf(var + BN_EPS) * g1[t];
        stats[64 + t] = sc;
        stats[96 + t] = b1[t] - mu * sc;
    }
}

// per-voxel: zxm = packed bf16 of relu(affine(xm)) — hoists per-point work
__global__ void k_xmz(const unsigned* __restrict__ xmraw,
                      const float* __restrict__ stats, unsigned* __restrict__ zxm) {
    int tid = blockIdx.x * 256 + threadIdx.x;  // NVOX*4
    int v = tid >> 2, q = tid & 3;             // channels 8q..8q+7
    uint4 a = ((const uint4*)xmraw)[v * 8 + q * 2];
    uint4 b = ((const uint4*)xmraw)[v * 8 + q * 2 + 1];
    float4 sc0 = ((const float4*)(stats + 64))[q * 2];
    float4 sh0 = ((const float4*)(stats + 96))[q * 2];
    float4 sc1 = ((const float4*)(stats + 64))[q * 2 + 1];
    float4 sh1 = ((const float4*)(stats + 96))[q * 2 + 1];
    uint4 o;
    o.x = packbf(fmaxf(0.f, fmaf(funkey(a.x), sc0.x, sh0.x)),
                 fmaxf(0.f, fmaf(funkey(a.y), sc0.y, sh0.y)));
    o.y = packbf(fmaxf(0.f, fmaf(funkey(a.z), sc0.z, sh0.z)),
                 fmaxf(0.f, fmaf(funkey(a.w), sc0.w, sh0.w)));
    o.z = packbf(fmaxf(0.f, fmaf(funkey(b.x), sc1.x, sh1.x)),
                 fmaxf(0.f, fmaf(funkey(b.y), sc1.y, sh1.y)));
    o.w = packbf(fmaxf(0.f, fmaf(funkey(b.z), sc1.z, sh1.z)),
                 fmaxf(0.f, fmaf(funkey(b.w), sc1.w, sh1.w)));
    ((uint4*)zxm)[v * 4 + q] = o;
}

// k_l2: load y1 bf16 + prepacked zxm -> per-wave Abuf -> MFMA -> y2t (aliased)
// -> boundary-mask segmented max (branch is WAVE-UNIFORM here: r is lane-
// independent, so the in-branch shfl has all lanes active) + BN2 partials.
__global__ __launch_bounds__(256) void k_l2(
    const int* __restrict__ svid, const unsigned* __restrict__ y1bf,
    const unsigned* __restrict__ zxm, const uint4* __restrict__ wfrag,
    const float* __restrict__ stats, float* __restrict__ spart2,
    unsigned* __restrict__ okeys) {
    __shared__ unsigned shbuf[4][1088];   // Abuf [32][32] then y2t [64][17]
    int t = threadIdx.x;
    int lane = t & 63, wave = t >> 6;
    int rl = lane & 31, half = lane >> 5;
    int lr = lane & 15, lk = lane >> 4;
    long brow = (long)blockIdx.x * 128 + wave * 32;
    int vid = svid[brow + rl];
    int vprev = __shfl(vid, (lane + 63) & 63);
    unsigned mask32 = (unsigned)(__ballot(rl > 0 && vid != vprev) & 0xFFFFFFFFull);

    // independent loads first: w2 fragments + y1 row-half + zxm row-half
    uint4 bw[8];
    #pragma unroll
    for (int q = 0; q < 8; ++q) bw[q] = wfrag[q * 64 + lane];
    uint4 yu0 = ((const uint4*)y1bf)[(brow + rl) * 4 + half * 2];
    uint4 yu1 = ((const uint4*)y1bf)[(brow + rl) * 4 + half * 2 + 1];
    uint4 xa = make_uint4(0, 0, 0, 0), xb = make_uint4(0, 0, 0, 0);
    if (vid >= 0) {
        xa = ((const uint4*)zxm)[(size_t)vid * 4 + half * 2];
        xb = ((const uint4*)zxm)[(size_t)vid * 4 + half * 2 + 1];
    }

    unsigned zpk[8];
    if (vid >= 0) {
        unsigned yw[8] = {yu0.x, yu0.y, yu0.z, yu0.w, yu1.x, yu1.y, yu1.z, yu1.w};
        #pragma unroll
        for (int q = 0; q < 4; ++q) {
            float4 sc = ((const float4*)(stats + 64))[half * 4 + q];
            float4 sh = ((const float4*)(stats + 96))[half * 4 + q];
            float yA = bf2f((unsigned short)(yw[2 * q] & 0xFFFF));
            float yB = bf2f((unsigned short)(yw[2 * q] >> 16));
            float yC = bf2f((unsigned short)(yw[2 * q + 1] & 0xFFFF));
            float yD = bf2f((unsigned short)(yw[2 * q + 1] >> 16));
            zpk[2 * q + 0] = packbf(fmaxf(0.f, fmaf(yA, sc.x, sh.x)),
                                    fmaxf(0.f, fmaf(yB, sc.y, sh.y)));
            zpk[2 * q + 1] = packbf(fmaxf(0.f, fmaf(yC, sc.z, sh.z)),
                                    fmaxf(0.f, fmaf(yD, sc.w, sh.w)));
        }
    } else {
        #pragma unroll
        for (int q = 0; q < 8; ++q) zpk[q] = 0u;
    }
    {
        uint4* arow = (uint4*)&shbuf[wave][rl * 32];
        int sw = rl & 7;
        arow[(2 * half + 0) ^ sw] = *(const uint4*)&zpk[0];
        arow[(2 * half + 1) ^ sw] = *(const uint4*)&zpk[4];
        arow[(4 + 2 * half) ^ sw] = xa;
        arow[(5 + 2 * half) ^ sw] = xb;
    }
    asm volatile("s_waitcnt lgkmcnt(0)" ::: "memory");
    __builtin_amdgcn_sched_barrier(0);

    bf16x8 afr[2][2];
    #pragma unroll
    for (int mt = 0; mt < 2; ++mt)
        #pragma unroll
        for (int kt = 0; kt < 2; ++kt) {
            int riw = mt * 16 + lr;
            uint4 uu = ((const uint4*)&shbuf[wave][riw * 32])[(kt * 4 + lk) ^ (riw & 7)];
            afr[mt][kt] = __builtin_bit_cast(bf16x8, uu);
        }
    asm volatile("s_waitcnt lgkmcnt(0)" ::: "memory");
    __builtin_amdgcn_sched_barrier(0);

    f32x4 acc[2][4];
    #pragma unroll
    for (int mt = 0; mt < 2; ++mt)
        #pragma unroll
        for (int nt = 0; nt < 4; ++nt) {
            acc[mt][nt] = (f32x4){0.f, 0.f, 0.f, 0.f};
            #pragma unroll
            for (int kt = 0; kt < 2; ++kt)
                acc[mt][nt] = __builtin_amdgcn_mfma_f32_16x16x32_bf16(
                    afr[mt][kt], __builtin_bit_cast(bf16x8, bw[nt * 2 + kt]),
                    acc[mt][nt], 0, 0, 0);
        }

    // y2t store (bf16 pairs) into the SAME buffer (Abuf dead now)
    unsigned* y2w = &shbuf[wave][0];
    #pragma unroll
    for (int mt = 0; mt < 2; ++mt)
        #pragma unroll
        for (int nt = 0; nt < 4; ++nt) {
            int col = nt * 16 + lr;
            int w0 = mt * 8 + lk * 2;
            y2w[col * 17 + w0] = packbf(acc[mt][nt][0], acc[mt][nt][1]);
            y2w[col * 17 + w0 + 1] = packbf(acc[mt][nt][2], acc[mt][nt][3]);
        }

    // BN2 partials (exact f32)
    {
        float sa[4] = {0.f, 0.f, 0.f, 0.f}, sq[4] = {0.f, 0.f, 0.f, 0.f};
        #pragma unroll
        for (int mt = 0; mt < 2; ++mt)
            #pragma unroll
            for (int nt = 0; nt < 4; ++nt)
                #pragma unroll
                for (int e = 0; e < 4; ++e) {
                    float v = acc[mt][nt][e];
                    sa[nt] += v; sq[nt] += v * v;
                }
        #pragma unroll
        for (int nt = 0; nt < 4; ++nt) {
            sa[nt] += __shfl_xor(sa[nt], 16); sa[nt] += __shfl_xor(sa[nt], 32);
            sq[nt] += __shfl_xor(sq[nt], 16); sq[nt] += __shfl_xor(sq[nt], 32);
        }
        if (lk == 0) {
            int slot = (blockIdx.x * 4 + wave) & 255;
            #pragma unroll
            for (int nt = 0; nt < 4; ++nt) {
                atomicAdd(&spart2[slot * 128 + nt * 16 + lr], sa[nt]);
                atomicAdd(&spart2[slot * 128 + 64 + nt * 16 + lr], sq[nt]);
            }
        }
    }
    asm volatile("s_waitcnt lgkmcnt(0)" ::: "memory");
    __builtin_amdgcn_sched_barrier(0);

    // boundary-mask segmented max over own 32 rows; channel = lane
    {
        int c = lane;
        float cur_m = 0.f; bool first = true;
        #pragma unroll
        for (int q = 0; q < 16; ++q) {
            unsigned u = y2w[c * 17 + q];
            #pragma unroll
            for (int e = 0; e < 2; ++e) {
                int r = 2 * q + e;
                float d = bf2f((unsigned short)(e ? (u >> 16) : (u & 0xFFFF)));
                if (r == 0) cur_m = d;
                else if ((mask32 >> r) & 1u) {
                    int v = __shfl(vid, r - 1);   // uniform branch: all lanes active
                    flush64(v, cur_m, first, c, okeys);
                    first = false; cur_m = d;
                } else cur_m = fmaxf(cur_m, d);
            }
        }
        int vlast = __shfl(vid, 31);
        flush64(vlast, cur_m, true, c, okeys);
    }
}

__global__ void k_fin2(const float* __restrict__ spart2, float* __restrict__ stats,
                       const float* __restrict__ g2, const float* __restrict__ b2) {
    __shared__ float cs[128];
    int t = threadIdx.x;
    float s = 0.f;
    for (int r = 0; r < 256; ++r) s += spart2[r * 128 + t];
    cs[t] = s;
    __syncthreads();
    if (t < 64) {
        float invn = 1.0f / (float)NPTS;
        float mu = cs[t] * invn;
        float var = cs[64 + t] * invn - mu * mu;
        float sc = rsqrtf(var + BN_EPS) * g2[t];
        stats[256 + t] = sc;
        stats[320 + t] = b2[t] - mu * sc;
    }
}

__global__ void k_out(unsigned* __restrict__ okeys, const float* __restrict__ stats) {
    int i4 = blockIdx.x * 256 + threadIdx.x;  // < NVOX*16
    uint4 u = ((const uint4*)okeys)[i4];
    int c0 = (i4 & 15) * 4;
    float4 o;
    o.x = fmaxf(0.f, fmaf(funkey(u.x), stats[256 + c0 + 0], stats[320 + c0 + 0]));
    o.y = fmaxf(0.f, fmaf(funkey(u.y), stats[256 + c0 + 1], stats[320 + c0 + 1]));
    o.z = fmaxf(0.f, fmaf(funkey(u.z), stats[256 + c0 + 2], stats[320 + c0 + 2]));
    o.w = fmaxf(0.f, fmaf(funkey(u.w), stats[256 + c0 + 3], stats[320 + c0 + 3]));
    ((float4*)okeys)[i4] = o;
}

extern "C" void kernel_launch(void* const* d_in, const int* in_sizes, int n_in,
                              void* d_out, int out_size, void* d_ws, size_t ws_size,
                              hipStream_t stream) {
    const float* xyz = (const float*)d_in[0];
    const float* pf  = (const float*)d_in[1];
    const float* w1  = (const float*)d_in[2];
    const float* g1  = (const float*)d_in[3];
    const float* b1  = (const float*)d_in[4];
    const float* w2  = (const float*)d_in[5];
    const float* g2  = (const float*)d_in[6];
    const float* b2  = (const float*)d_in[7];
    const int*   unq = (const int*)d_in[8];

    float4* spts     = (float4*)d_ws;                        // PAD float4 (24 MB)
    float4* vmeanv   = spts + PAD;                           // NVOX float4 (4 MB)
    int* svid        = (int*)(vmeanv + NVOX);                // PAD ints (6 MB)
    unsigned* xmraw  = (unsigned*)(svid + PAD);              // NVOX*32 f32-fkeys (32 MB)
    int* cntv        = (int*)(xmraw + (size_t)NVOX * 32);    // NVOX
    int* startv      = cntv + NVOX;                          // NVOX
    int* offv        = startv + NVOX;                        // NVOX
    int* bsum        = offv + NVOX;                          // 256
    float* stats     = (float*)(bsum + 256);                 // 1024
    float* spart1    = stats + 1024;                         // 256*64
    float* spart2    = spart1 + 256 * 64;                    // 256*128
    uint4* wfrag     = (uint4*)(spart2 + 256 * 128);         // 8*64 uint4
    unsigned* y1bf   = (unsigned*)(wfrag + 512);             // PAD*16 uints (96 MB)
    // zxm (16 MB) aliases spts (24 MB): spts dead after k_passA, k_xmz after.
    unsigned* zxm    = (unsigned*)spts;

    unsigned* okeys = (unsigned*)d_out;

    k_init<<<2048, 256, 0, stream>>>(okeys, xmraw, cntv, stats, svid, w2, wfrag);
    k_hist<<<NB_PT, 256, 0, stream>>>(unq, cntv);
    k_scanA<<<256, 256, 0, stream>>>(cntv, startv, bsum);
    k_scanC<<<256, 256, 0, stream>>>(startv, offv, bsum);
    k_scatter2<<<NB_PT, 256, 0, stream>>>(xyz, pf, unq, offv, spts, svid);
    k_vmean2<<<NVOX / 256, 256, 0, stream>>>(spts, cntv, startv, vmeanv);
    k_passA<<<NB_L2, 256, 0, stream>>>(spts, svid, vmeanv, w1, xmraw, y1bf, spart1);
    k_fin1<<<1, 64, 0, stream>>>(spart1, stats, g1, b1);
    k_xmz<<<NVOX * 4 / 256, 256, 0, stream>>>(xmraw, stats, zxm);
    k_l2<<<NB_L2, 256, 0, stream>>>(svid, y1bf, zxm, wfrag, stats, spart2, okeys);
    k_fin2<<<1, 128, 0, stream>>>(spart2, stats, g2, b2);
    k_out<<<NVOX * 16 / 256, 256, 0, stream>>>(okeys, stats);
}